// Round 11
// baseline (90.412 us; speedup 1.0000x reference)
//
#include <hip/hip_runtime.h>
#include <math.h>

#define B 4
#define C 64
#define HW 4096

typedef _Float16 f16;
typedef f16 f16x8 __attribute__((ext_vector_type(8)));
typedef f16 f16x4 __attribute__((ext_vector_type(4)));
typedef float f32x4 __attribute__((ext_vector_type(4)));
typedef float f32x16 __attribute__((ext_vector_type(16)));
typedef int i32x4 __attribute__((ext_vector_type(4)));
typedef f16x8 f16x8a __attribute__((aligned(8)));   // 8B-aligned vector loads

#define MFMA16(a,b,c) __builtin_amdgcn_mfma_f32_16x16x32_f16(a,b,c,0,0,0)
#define MFMA32(a,b,c) __builtin_amdgcn_mfma_f32_32x32x16_f16(a,b,c,0,0,0)

// ws layout (~20.4 MB; ws_size ~256 MB per observed poison fill):
//   et16    : [B][HW][C] f16  (e, i-major)           2 MB
//   ec16    : [B][C][HW] f16  (e, c-major)           2 MB
//   mbuf    : [B][HW] f32     (m~ = f16-rounded |e_i|^2)  64 KB
//   lpartial: [B][HW][4] f32  (split-j exp sums)     256 KB
//   partial : [8][B][HW][C] f16  (out^T per iq)      16 MB

// XCD-affine swizzles (8 XCDs x k contiguous logical blocks).
__device__ __forceinline__ int swz_blk()     { int r = blockIdx.x; return (r & 7) * 32  + (r >> 3); }
__device__ __forceinline__ int swz_blk512()  { int r = blockIdx.x; return (r & 7) * 64  + (r >> 3); }
__device__ __forceinline__ int swz_blk1024() { int r = blockIdx.x; return (r & 7) * 128 + (r >> 3); }

// ---------------- Kernel A: e = W @ x + bconv -> et16, ec16, mbuf -------------------
__global__ __launch_bounds__(256) void k_e(
    const float* __restrict__ x, const float* __restrict__ W,
    const float* __restrict__ bconv, f16* __restrict__ et, f16* __restrict__ ec,
    float* __restrict__ mbuf)
{
  __shared__ float Ws[64][65];
  __shared__ float xs[64][64];
  __shared__ __align__(16) f16 es[64][72];
  __shared__ float msp[4][64];
  const int blk = swz_blk();
  const int b = blk >> 6;
  const int i0 = (blk & 63) * 64;
  const int tid = threadIdx.x;

  for (int k = tid; k < 64 * 64; k += 256) Ws[k >> 6][k & 63] = W[k];
  for (int k = tid; k < 64 * 64; k += 256)
    xs[k >> 6][k & 63] = x[((size_t)b * C + (k >> 6)) * HW + i0 + (k & 63)];
  __syncthreads();

  const int o = tid & 63;
  const int ig = tid >> 6;
  float acc[16];
  float bv = bconv[o];
  #pragma unroll
  for (int k = 0; k < 16; ++k) acc[k] = bv;
  for (int c = 0; c < C; ++c) {
    float wv = Ws[o][c];
    #pragma unroll
    for (int k = 0; k < 16; ++k) acc[k] = fmaf(wv, xs[c][ig * 16 + k], acc[k]);
  }
  #pragma unroll
  for (int k = 0; k < 16; ++k) {
    int ii = ig * 16 + k;
    f16 v = (f16)acc[k];
    et[((size_t)b * HW + i0 + ii) * C + o] = v;
    es[o][ii] = v;
  }
  __syncthreads();

  // ec transpose (f16x4 vectorized stores)
  {
    const int ii4 = (tid & 15) * 4;
    const int ob = tid >> 4;
    #pragma unroll
    for (int k = 0; k < 4; ++k) {
      int oo = ob + 16 * k;
      f16x4 v = *(const f16x4*)&es[oo][ii4];
      *(f16x4*)&ec[((size_t)b * C + oo) * HW + i0 + ii4] = v;
    }
  }

  // m_i = |e_i|^2 (sum over channels, fp32 accum)
  const int ii = tid & 63, og = tid >> 6;
  {
    float s = 0.f;
    #pragma unroll
    for (int k = 0; k < 16; ++k) {
      float v = (float)es[og * 16 + k][ii];
      s = fmaf(v, v, s);
    }
    msp[og][ii] = s;
  }
  __syncthreads();
  if (tid < 64) {
    float mm = msp[0][tid] + msp[1][tid] + msp[2][tid] + msp[3][tid];
    // canonicalize the shift to f16 (k_out applies it through an f16 MFMA operand)
    mbuf[(size_t)b * HW + i0 + tid] = (float)(f16)mm;
  }
}

// ---------------- Kernel B: split-j softmax partials -------------------------------
// 1024 blocks = (b:4, ib:64 of 64 i-rows, jq:4 of 1024 j) x 256 thr (4 waves).
// lpartial[b][i][jq] = sum_{j in jq quarter} exp(s_ij - m~_i).  ~95 VGPR <= 128 cap.
__global__ __launch_bounds__(256) __attribute__((amdgpu_waves_per_eu(4, 4)))
void k_stats(const f16* __restrict__ et, const float* __restrict__ mbuf,
             float* __restrict__ lpartial)
{
  __shared__ float lpart[4][68];
  const int blk = swz_blk1024();
  const int b  = blk >> 8;
  const int ib = (blk >> 2) & 63;
  const int jq = blk & 3;
  const int i0 = ib * 64;
  const int tid = threadIdx.x;
  const int wv = tid >> 6;
  const int lane = tid & 63;
  const int lr = lane & 15, lg = lane >> 4;
  const f16* etb = et + (size_t)b * HW * C;

  // A-fragments: the block's 64 i-rows (4 subtiles x 2 K-chunks)
  f16x8 a[4][2];
  #pragma unroll
  for (int is = 0; is < 4; ++is)
    #pragma unroll
    for (int kc = 0; kc < 2; ++kc)
      a[is][kc] = *(const f16x8*)(etb + (size_t)(i0 + is * 16 + lr) * C + kc * 32 + lg * 8);

  // softmax shifts (f16-canonical, from k_e)
  f32x4 ms4[4];
  #pragma unroll
  for (int is = 0; is < 4; ++is)
    ms4[is] = *(const f32x4*)(mbuf + (size_t)b * HW + i0 + is * 16 + lg * 4);

  // sweep this block's 1024-j quarter: wave wv takes 32-j tiles wv+4t
  float lacc[4][4] = {};
  for (int t = 0; t < 8; ++t) {
    const int j0 = jq * 1024 + (wv + 4 * t) * 32;
    #pragma unroll
    for (int js = 0; js < 2; ++js) {
      f16x8 b0 = *(const f16x8*)(etb + (size_t)(j0 + js * 16 + lr) * C + lg * 8);
      f16x8 b1 = *(const f16x8*)(etb + (size_t)(j0 + js * 16 + lr) * C + 32 + lg * 8);
      #pragma unroll
      for (int is = 0; is < 4; ++is) {
        f32x4 z = {0.f, 0.f, 0.f, 0.f};
        f32x4 S = MFMA16(a[is][0], b0, z);
        S = MFMA16(a[is][1], b1, S);
        #pragma unroll
        for (int r = 0; r < 4; ++r) lacc[is][r] += __expf(S[r] - ms4[is][r]);
      }
    }
  }

  // reduce over the 16 j-columns held by lanes sharing lg
  #pragma unroll
  for (int m = 1; m < 16; m <<= 1)
    #pragma unroll
    for (int is = 0; is < 4; ++is)
      #pragma unroll
      for (int r = 0; r < 4; ++r) lacc[is][r] += __shfl_xor(lacc[is][r], m);

  if (lr == 0)
    #pragma unroll
    for (int is = 0; is < 4; ++is)
      #pragma unroll
      for (int r = 0; r < 4; ++r) lpart[wv][is * 16 + lg * 4 + r] = lacc[is][r];
  __syncthreads();

  if (tid < 64)
    lpartial[((size_t)b * HW + i0 + tid) * 4 + jq] =
        lpart[0][tid] + lpart[1][tid] + lpart[2][tid] + lpart[3][tid];
}

// ---------------- Kernel C: partial^T[iq] += P^T . e^T  (out^T = sum_i) -------------
// 512 blocks = (b:4, jb:16 of 256 j, iq:8 of 512 i). 256 thr = 4 waves, 64 j per wave.
// Doubling j-per-wave halves LDS-read cycles per MFMA (af/bv reads amortized over 18
// MFMAs instead of 9). waves_per_eu(2,4): allocator budget 256 VGPR -> no forced spill.
#define ETS 68   // etL row stride (f16)
#define ECS 36   // ecL row stride
__global__ __launch_bounds__(256) __attribute__((amdgpu_waves_per_eu(2, 4)))
void k_out(
    const f16* __restrict__ et, const f16* __restrict__ ec,
    const float* __restrict__ mbuf, const float* __restrict__ lpartial,
    f16* __restrict__ partial)
{
  __shared__ __align__(16) f16 etL[2][32][ETS];    // [i][c]
  __shared__ __align__(16) f16 ecL[2][64][ECS];    // [c][i]
  __shared__ __align__(16) f16 maugAll[513][8];    // [m~, dhi, dlo, 0...]; row 512 = zeros
  const int blk = swz_blk512();
  const int b  = blk >> 7;
  const int jb = (blk >> 3) & 15;
  const int iq = blk & 7;
  const int tid = threadIdx.x;
  const int w = tid >> 6;          // 0..3
  const int lane = tid & 63;
  const int l31 = lane & 31;
  const int h = lane >> 5;
  const int jbase = jb * 256 + w * 64;   // wave owns 64 j (2 jt tiles of 32)
  const int ibase = iq * 512;

  const f16* etb = et + (size_t)b * HW * C;
  const f16* ecb = ec + (size_t)b * C * HW;

  // per-i softmax constants for the block's 512 i (2 rows per thread)
  #pragma unroll
  for (int rr = 0; rr < 2; ++rr) {
    int i = tid + rr * 256;
    float m = mbuf[(size_t)b * HW + ibase + i];
    f32x4 lp = *(const f32x4*)&lpartial[((size_t)b * HW + ibase + i) * 4];
    float l = lp[0] + lp[1] + lp[2] + lp[3];
    float d = __logf(l);
    f16 dh = (f16)d;
    f16 dl = (f16)(d - (float)dh);
    f16x8 row = {};
    row[0] = (f16)m; row[1] = dh; row[2] = dl;
    *(f16x8*)&maugAll[i][0] = row;
  }
  if (tid == 0) { f16x8 zz = {}; *(f16x8*)&maugAll[512][0] = zz; }

  // constant aug B-fragment: -1 at k_local 0,1,2 (h=0 lanes), 0 elsewhere
  f16x8 baug = {};
  if (h == 0) { baug[0] = (f16)-1.f; baug[1] = (f16)-1.f; baug[2] = (f16)-1.f; }

  // score B fragments (regs, fixed): 2 jt tiles x 4 K-chunks of 16 c
  f16x8 bj[2][4];
  #pragma unroll
  for (int jt = 0; jt < 2; ++jt)
    #pragma unroll
    for (int kc = 0; kc < 4; ++kc)
      bj[jt][kc] = *(const f16x8*)(etb + (size_t)(jbase + jt * 32 + l31) * C + kc * 16 + h * 8);

  f32x16 acc[2][2] = {};   // [jt][cs] of out^T (m=j, n=c)

  // staging: EVERY thread stages one et vector and one ec vector per chunk
  const int sei = tid >> 3;          // et row 0..31
  const int sec = (tid & 7) * 8;     // et col
  const int scc = tid >> 2;          // ec row (c) 0..63
  const int sci = (tid & 3) * 8;     // ec col (i)

  // prologue: stage chunk 0
  *(f16x8a*)&etL[0][sei][sec] = *(const f16x8*)(etb + (size_t)(ibase + sei) * C + sec);
  *(f16x8a*)&ecL[0][scc][sci] = *(const f16x8*)(ecb + (size_t)scc * HW + ibase + sci);
  __syncthreads();

  for (int t = 0; t < 16; ++t) {
    const int cur = t & 1;
    const int i0c = ibase + t * 32;

    // issue next chunk's global loads early
    f16x8 sve, svc;
    if (t < 15) {
      sve = *(const f16x8*)(etb + (size_t)(i0c + 32 + sei) * C + sec);
      svc = *(const f16x8*)(ecb + (size_t)scc * HW + (i0c + 32) + sci);
    }

    // PV B fragments (e^T): B[k=i][n=c] from ecL
    f16x8 bv[2][2];
    #pragma unroll
    for (int cs = 0; cs < 2; ++cs)
      #pragma unroll
      for (int kf = 0; kf < 2; ++kf)
        bv[cs][kf] = *(const f16x8a*)&ecL[cur][cs * 32 + l31][kf * 16 + h * 8];

    // score A fragments: A[m=i][k=c] from etL, + aug fragment
    f16x8 af[4];
    #pragma unroll
    for (int kc = 0; kc < 4; ++kc)
      af[kc] = *(const f16x8a*)&etL[cur][l31][kc * 16 + h * 8];
    f16x8 aaug = *(const f16x8*)&maugAll[h ? 512 : (t * 32 + l31)][0];

    #pragma unroll
    for (int jt = 0; jt < 2; ++jt) {
      // S' = e_i . e_j - m~_i - ln(l_i)
      f32x16 z = {};
      f32x16 S = MFMA32(af[0], bj[jt][0], z);
      S = MFMA32(af[1], bj[jt][1], S);
      S = MFMA32(af[2], bj[jt][2], S);
      S = MFMA32(af[3], bj[jt][3], S);
      S = MFMA32(aaug, baug, S);

      // P = exp(S'); repack to PV A-frag (lane=j, k=i) via pkrtz + permlane32_swap
      f16x8 pa[2];
      #pragma unroll
      for (int kf = 0; kf < 2; ++kf) {
        int A0 = __builtin_bit_cast(int, __builtin_amdgcn_cvt_pkrtz(__expf(S[kf * 8 + 0]), __expf(S[kf * 8 + 1])));
        int A1 = __builtin_bit_cast(int, __builtin_amdgcn_cvt_pkrtz(__expf(S[kf * 8 + 2]), __expf(S[kf * 8 + 3])));
        int B0 = __builtin_bit_cast(int, __builtin_amdgcn_cvt_pkrtz(__expf(S[kf * 8 + 4]), __expf(S[kf * 8 + 5])));
        int B1 = __builtin_bit_cast(int, __builtin_amdgcn_cvt_pkrtz(__expf(S[kf * 8 + 6]), __expf(S[kf * 8 + 7])));
        // HW semantic: vdst.hi <-> vsrc.lo. vdst=A (low rows), vsrc=B (high rows).
        asm volatile("v_permlane32_swap_b32 %0, %1" : "+v"(A0), "+v"(B0));
        asm volatile("v_permlane32_swap_b32 %0, %1" : "+v"(A1), "+v"(B1));
        i32x4 fri = {A0, A1, B0, B1};
        pa[kf] = __builtin_bit_cast(f16x8, fri);
      }

      acc[jt][0] = MFMA32(pa[0], bv[0][0], acc[jt][0]);
      acc[jt][1] = MFMA32(pa[0], bv[1][0], acc[jt][1]);
      acc[jt][0] = MFMA32(pa[1], bv[0][1], acc[jt][0]);
      acc[jt][1] = MFMA32(pa[1], bv[1][1], acc[jt][1]);
    }

    // stage write for next chunk
    if (t < 15) {
      *(f16x8a*)&etL[cur ^ 1][sei][sec] = sve;
      *(f16x8a*)&ecL[cur ^ 1][scc][sci] = svc;
    }
    __syncthreads();
  }

  // partial[iq][b][j][c] (out^T layout -> coalesced: lanes vary c)
  f16* pb = partial + (size_t)(iq * B + b) * HW * C;
  #pragma unroll
  for (int jt = 0; jt < 2; ++jt)
    #pragma unroll
    for (int cs = 0; cs < 2; ++cs)
      #pragma unroll
      for (int r = 0; r < 16; ++r) {
        int j = jbase + jt * 32 + (r & 3) + 8 * (r >> 2) + 4 * h;
        pb[(size_t)j * C + cs * 32 + l31] = (f16)acc[jt][cs][r];
      }
}

// ---------------- Kernel D: out[c][j] = x + sum_iq partial[iq][j][c] (transpose) ----
__global__ __launch_bounds__(256) void k_reduce(
    const f16* __restrict__ partial, const float* __restrict__ x, float* __restrict__ out)
{
  __shared__ float tile[64][65];
  const int blk = swz_blk();
  const int b = blk >> 6;
  const int j0 = (blk & 63) * 64;
  const int tid = threadIdx.x;
  const int jj = tid >> 2, cq = (tid & 3) * 16;

  float a0[16] = {};
  for (int iq = 0; iq < 8; ++iq) {
    const f16* p = partial + ((size_t)(iq * B + b) * HW + j0 + jj) * C + cq;
    f16x8 v0 = *(const f16x8*)p;
    f16x8 v1 = *(const f16x8*)(p + 8);
    #pragma unroll
    for (int e = 0; e < 8; ++e) { a0[e] += (float)v0[e]; a0[8 + e] += (float)v1[e]; }
  }
  #pragma unroll
  for (int e = 0; e < 16; ++e) tile[jj][cq + e] = a0[e];
  __syncthreads();

  const int c = tid >> 2, jq = (tid & 3) * 16;
  #pragma unroll
  for (int k = 0; k < 4; ++k) {
    size_t idx = ((size_t)b * C + c) * HW + j0 + jq + k * 4;
    float4 xv = *(const float4*)(x + idx);
    float4 ov;
    ov.x = tile[jq + k * 4 + 0][c] + xv.x;
    ov.y = tile[jq + k * 4 + 1][c] + xv.y;
    ov.z = tile[jq + k * 4 + 2][c] + xv.z;
    ov.w = tile[jq + k * 4 + 3][c] + xv.w;
    *(float4*)(out + idx) = ov;
  }
}

extern "C" void kernel_launch(void* const* d_in, const int* in_sizes, int n_in,
                              void* d_out, int out_size, void* d_ws, size_t ws_size,
                              hipStream_t stream) {
  const float* x = (const float*)d_in[0];
  const float* W = (const float*)d_in[1];
  const float* bconv = (const float*)d_in[2];
  float* out = (float*)d_out;

  f16* et16 = (f16*)d_ws;
  f16* ec16 = et16 + (size_t)B * HW * C;
  float* mbuf = (float*)(ec16 + (size_t)B * HW * C);
  float* lpartial = mbuf + (size_t)B * HW;               // [B][HW][4] f32
  f16* partial = (f16*)(lpartial + (size_t)B * HW * 4);  // 16 MB; ws total ~20.4 MB

  k_e<<<dim3(256), dim3(256), 0, stream>>>(x, W, bconv, et16, ec16, mbuf);
  k_stats<<<dim3(1024), dim3(256), 0, stream>>>(et16, mbuf, lpartial);
  k_out<<<dim3(512), dim3(256), 0, stream>>>(et16, ec16, mbuf, lpartial, partial);
  k_reduce<<<dim3(256), dim3(256), 0, stream>>>(partial, x, out);
}

// Round 12
// 73.572 us; speedup vs baseline: 1.2289x; 1.2289x over previous
//
#include <hip/hip_runtime.h>
#include <math.h>

#define B 4
#define C 64
#define HW 4096

typedef _Float16 f16;
typedef f16 f16x8 __attribute__((ext_vector_type(8)));
typedef f16 f16x4 __attribute__((ext_vector_type(4)));
typedef float f32x4 __attribute__((ext_vector_type(4)));
typedef float f32x16 __attribute__((ext_vector_type(16)));
typedef int i32x4 __attribute__((ext_vector_type(4)));
typedef f16x8 f16x8a __attribute__((aligned(8)));   // 8B-aligned vector loads

#define MFMA16(a,b,c) __builtin_amdgcn_mfma_f32_16x16x32_f16(a,b,c,0,0,0)
#define MFMA32(a,b,c) __builtin_amdgcn_mfma_f32_32x32x16_f16(a,b,c,0,0,0)

// ws layout (~20.4 MB):
//   et16    : [B][HW][C] f16  (e, i-major)           2 MB
//   ec16    : [B][C][HW] f16  (e, c-major)           2 MB
//   mbuf    : [B][HW] f32     (m~ = f16-rounded |e_i|^2)  64 KB
//   lpartial: [B][HW][4] f32  (split-j exp sums)     256 KB
//   partial : [8][B][HW][C] f16  (out^T per iq)      16 MB
//
// HARD-WON RULE (rounds 4/6/7/10): this target pins k_stats-like kernels at 64 VGPR
// no matter what launch_bounds/waves_per_eu say. Size per-thread live state to fit 64
// (32 i-rows max) or it spills ~200 MB of scratch and costs 50 us.

// XCD-affine swizzles (8 XCDs x k contiguous logical blocks).
__device__ __forceinline__ int swz_blk()     { int r = blockIdx.x; return (r & 7) * 32  + (r >> 3); }
__device__ __forceinline__ int swz_blk512()  { int r = blockIdx.x; return (r & 7) * 64  + (r >> 3); }
__device__ __forceinline__ int swz_blk2048() { int r = blockIdx.x; return (r & 7) * 256 + (r >> 3); }

// ---------------- Kernel A: e = W @ x + bconv -> et16, ec16, mbuf -------------------
__global__ __launch_bounds__(256) void k_e(
    const float* __restrict__ x, const float* __restrict__ W,
    const float* __restrict__ bconv, f16* __restrict__ et, f16* __restrict__ ec,
    float* __restrict__ mbuf)
{
  __shared__ float Ws[64][65];
  __shared__ float xs[64][64];
  __shared__ __align__(16) f16 es[64][72];
  __shared__ float msp[4][64];
  const int blk = swz_blk();
  const int b = blk >> 6;
  const int i0 = (blk & 63) * 64;
  const int tid = threadIdx.x;

  for (int k = tid; k < 64 * 64; k += 256) Ws[k >> 6][k & 63] = W[k];
  for (int k = tid; k < 64 * 64; k += 256)
    xs[k >> 6][k & 63] = x[((size_t)b * C + (k >> 6)) * HW + i0 + (k & 63)];
  __syncthreads();

  const int o = tid & 63;
  const int ig = tid >> 6;
  float acc[16];
  float bv = bconv[o];
  #pragma unroll
  for (int k = 0; k < 16; ++k) acc[k] = bv;
  for (int c = 0; c < C; ++c) {
    float wv = Ws[o][c];
    #pragma unroll
    for (int k = 0; k < 16; ++k) acc[k] = fmaf(wv, xs[c][ig * 16 + k], acc[k]);
  }
  #pragma unroll
  for (int k = 0; k < 16; ++k) {
    int ii = ig * 16 + k;
    f16 v = (f16)acc[k];
    et[((size_t)b * HW + i0 + ii) * C + o] = v;
    es[o][ii] = v;
  }
  __syncthreads();

  // ec transpose (f16x4 vectorized stores)
  {
    const int ii4 = (tid & 15) * 4;
    const int ob = tid >> 4;
    #pragma unroll
    for (int k = 0; k < 4; ++k) {
      int oo = ob + 16 * k;
      f16x4 v = *(const f16x4*)&es[oo][ii4];
      *(f16x4*)&ec[((size_t)b * C + oo) * HW + i0 + ii4] = v;
    }
  }

  // m_i = |e_i|^2 (sum over channels, fp32 accum)
  const int ii = tid & 63, og = tid >> 6;
  {
    float s = 0.f;
    #pragma unroll
    for (int k = 0; k < 16; ++k) {
      float v = (float)es[og * 16 + k][ii];
      s = fmaf(v, v, s);
    }
    msp[og][ii] = s;
  }
  __syncthreads();
  if (tid < 64) {
    float mm = msp[0][tid] + msp[1][tid] + msp[2][tid] + msp[3][tid];
    // canonicalize the shift to f16 (k_out applies it through an f16 MFMA operand)
    mbuf[(size_t)b * HW + i0 + tid] = (float)(f16)mm;
  }
}

// ---------------- Kernel B: split-j softmax partials (round-9 proven config) --------
// 2048 blocks = (b:4, ib:128 of 32 i-rows, jq:4 of 1024 j) x 256 thr (4 waves).
// ~60 VGPR live -> fits the 64-VGPR pin, no spill (verified in the 74.1 us run).
__global__ __launch_bounds__(256) __attribute__((amdgpu_waves_per_eu(4, 4)))
void k_stats(const f16* __restrict__ et, const float* __restrict__ mbuf,
             float* __restrict__ lpartial)
{
  __shared__ float lpart[4][36];
  const int blk = swz_blk2048();
  const int b  = blk >> 9;
  const int ib = (blk >> 2) & 127;
  const int jq = blk & 3;
  const int i0 = ib * 32;
  const int tid = threadIdx.x;
  const int wv = tid >> 6;
  const int lane = tid & 63;
  const int lr = lane & 15, lg = lane >> 4;
  const f16* etb = et + (size_t)b * HW * C;

  // A-fragments: the block's 32 i-rows (2 subtiles x 2 K-chunks)
  f16x8 a[2][2];
  #pragma unroll
  for (int is = 0; is < 2; ++is)
    #pragma unroll
    for (int kc = 0; kc < 2; ++kc)
      a[is][kc] = *(const f16x8*)(etb + (size_t)(i0 + is * 16 + lr) * C + kc * 32 + lg * 8);

  // softmax shifts (f16-canonical, from k_e)
  f32x4 ms4[2];
  #pragma unroll
  for (int is = 0; is < 2; ++is)
    ms4[is] = *(const f32x4*)(mbuf + (size_t)b * HW + i0 + is * 16 + lg * 4);

  // sweep this block's 1024-j quarter: wave wv takes 32-j tiles wv+4t
  float lacc[2][4] = {};
  for (int t = 0; t < 8; ++t) {
    const int j0 = jq * 1024 + (wv + 4 * t) * 32;
    #pragma unroll
    for (int js = 0; js < 2; ++js) {
      f16x8 b0 = *(const f16x8*)(etb + (size_t)(j0 + js * 16 + lr) * C + lg * 8);
      f16x8 b1 = *(const f16x8*)(etb + (size_t)(j0 + js * 16 + lr) * C + 32 + lg * 8);
      #pragma unroll
      for (int is = 0; is < 2; ++is) {
        f32x4 z = {0.f, 0.f, 0.f, 0.f};
        f32x4 S = MFMA16(a[is][0], b0, z);
        S = MFMA16(a[is][1], b1, S);
        #pragma unroll
        for (int r = 0; r < 4; ++r) lacc[is][r] += __expf(S[r] - ms4[is][r]);
      }
    }
  }

  // reduce over the 16 j-columns held by lanes sharing lg
  #pragma unroll
  for (int m = 1; m < 16; m <<= 1)
    #pragma unroll
    for (int is = 0; is < 2; ++is)
      #pragma unroll
      for (int r = 0; r < 4; ++r) lacc[is][r] += __shfl_xor(lacc[is][r], m);

  if (lr == 0)
    #pragma unroll
    for (int is = 0; is < 2; ++is)
      #pragma unroll
      for (int r = 0; r < 4; ++r) lpart[wv][is * 16 + lg * 4 + r] = lacc[is][r];
  __syncthreads();

  if (tid < 32)
    lpartial[((size_t)b * HW + i0 + tid) * 4 + jq] =
        lpart[0][tid] + lpart[1][tid] + lpart[2][tid] + lpart[3][tid];
}

// ---------------- Kernel C: partial^T[iq] += P^T . e^T  (out^T = sum_i) -------------
// 512 blocks = (b:4, jb:16 of 256 j, iq:8 of 512 i). 256 thr = 4 waves, 64 j per wave.
#define ETS 68   // etL row stride (f16)
#define ECS 36   // ecL row stride
__global__ __launch_bounds__(256) __attribute__((amdgpu_waves_per_eu(2, 4)))
void k_out(
    const f16* __restrict__ et, const f16* __restrict__ ec,
    const float* __restrict__ mbuf, const float* __restrict__ lpartial,
    f16* __restrict__ partial)
{
  __shared__ __align__(16) f16 etL[2][32][ETS];    // [i][c]
  __shared__ __align__(16) f16 ecL[2][64][ECS];    // [c][i]
  __shared__ __align__(16) f16 maugAll[513][8];    // [m~, dhi, dlo, 0...]; row 512 = zeros
  const int blk = swz_blk512();
  const int b  = blk >> 7;
  const int jb = (blk >> 3) & 15;
  const int iq = blk & 7;
  const int tid = threadIdx.x;
  const int w = tid >> 6;          // 0..3
  const int lane = tid & 63;
  const int l31 = lane & 31;
  const int h = lane >> 5;
  const int jbase = jb * 256 + w * 64;   // wave owns 64 j (2 jt tiles of 32)
  const int ibase = iq * 512;

  const f16* etb = et + (size_t)b * HW * C;
  const f16* ecb = ec + (size_t)b * C * HW;

  // per-i softmax constants for the block's 512 i (2 rows per thread)
  #pragma unroll
  for (int rr = 0; rr < 2; ++rr) {
    int i = tid + rr * 256;
    float m = mbuf[(size_t)b * HW + ibase + i];
    f32x4 lp = *(const f32x4*)&lpartial[((size_t)b * HW + ibase + i) * 4];
    float l = lp[0] + lp[1] + lp[2] + lp[3];
    float d = __logf(l);
    f16 dh = (f16)d;
    f16 dl = (f16)(d - (float)dh);
    f16x8 row = {};
    row[0] = (f16)m; row[1] = dh; row[2] = dl;
    *(f16x8*)&maugAll[i][0] = row;
  }
  if (tid == 0) { f16x8 zz = {}; *(f16x8*)&maugAll[512][0] = zz; }

  // constant aug B-fragment: -1 at k_local 0,1,2 (h=0 lanes), 0 elsewhere
  f16x8 baug = {};
  if (h == 0) { baug[0] = (f16)-1.f; baug[1] = (f16)-1.f; baug[2] = (f16)-1.f; }

  // score B fragments (regs, fixed): 2 jt tiles x 4 K-chunks of 16 c
  f16x8 bj[2][4];
  #pragma unroll
  for (int jt = 0; jt < 2; ++jt)
    #pragma unroll
    for (int kc = 0; kc < 4; ++kc)
      bj[jt][kc] = *(const f16x8*)(etb + (size_t)(jbase + jt * 32 + l31) * C + kc * 16 + h * 8);

  f32x16 acc[2][2] = {};   // [jt][cs] of out^T (m=j, n=c)

  // staging: EVERY thread stages one et vector and one ec vector per chunk
  const int sei = tid >> 3;          // et row 0..31
  const int sec = (tid & 7) * 8;     // et col
  const int scc = tid >> 2;          // ec row (c) 0..63
  const int sci = (tid & 3) * 8;     // ec col (i)

  // prologue: stage chunk 0
  *(f16x8a*)&etL[0][sei][sec] = *(const f16x8*)(etb + (size_t)(ibase + sei) * C + sec);
  *(f16x8a*)&ecL[0][scc][sci] = *(const f16x8*)(ecb + (size_t)scc * HW + ibase + sci);
  __syncthreads();

  for (int t = 0; t < 16; ++t) {
    const int cur = t & 1;
    const int i0c = ibase + t * 32;

    // issue next chunk's global loads early
    f16x8 sve, svc;
    if (t < 15) {
      sve = *(const f16x8*)(etb + (size_t)(i0c + 32 + sei) * C + sec);
      svc = *(const f16x8*)(ecb + (size_t)scc * HW + (i0c + 32) + sci);
    }

    // PV B fragments (e^T): B[k=i][n=c] from ecL
    f16x8 bv[2][2];
    #pragma unroll
    for (int cs = 0; cs < 2; ++cs)
      #pragma unroll
      for (int kf = 0; kf < 2; ++kf)
        bv[cs][kf] = *(const f16x8a*)&ecL[cur][cs * 32 + l31][kf * 16 + h * 8];

    // score A fragments: A[m=i][k=c] from etL, + aug fragment
    f16x8 af[4];
    #pragma unroll
    for (int kc = 0; kc < 4; ++kc)
      af[kc] = *(const f16x8a*)&etL[cur][l31][kc * 16 + h * 8];
    f16x8 aaug = *(const f16x8*)&maugAll[h ? 512 : (t * 32 + l31)][0];

    #pragma unroll
    for (int jt = 0; jt < 2; ++jt) {
      // S' = e_i . e_j - m~_i - ln(l_i)
      f32x16 z = {};
      f32x16 S = MFMA32(af[0], bj[jt][0], z);
      S = MFMA32(af[1], bj[jt][1], S);
      S = MFMA32(af[2], bj[jt][2], S);
      S = MFMA32(af[3], bj[jt][3], S);
      S = MFMA32(aaug, baug, S);

      // P = exp(S'); repack to PV A-frag (lane=j, k=i) via pkrtz + permlane32_swap
      f16x8 pa[2];
      #pragma unroll
      for (int kf = 0; kf < 2; ++kf) {
        int A0 = __builtin_bit_cast(int, __builtin_amdgcn_cvt_pkrtz(__expf(S[kf * 8 + 0]), __expf(S[kf * 8 + 1])));
        int A1 = __builtin_bit_cast(int, __builtin_amdgcn_cvt_pkrtz(__expf(S[kf * 8 + 2]), __expf(S[kf * 8 + 3])));
        int B0 = __builtin_bit_cast(int, __builtin_amdgcn_cvt_pkrtz(__expf(S[kf * 8 + 4]), __expf(S[kf * 8 + 5])));
        int B1 = __builtin_bit_cast(int, __builtin_amdgcn_cvt_pkrtz(__expf(S[kf * 8 + 6]), __expf(S[kf * 8 + 7])));
        // HW semantic: vdst.hi <-> vsrc.lo. vdst=A (low rows), vsrc=B (high rows).
        asm volatile("v_permlane32_swap_b32 %0, %1" : "+v"(A0), "+v"(B0));
        asm volatile("v_permlane32_swap_b32 %0, %1" : "+v"(A1), "+v"(B1));
        i32x4 fri = {A0, A1, B0, B1};
        pa[kf] = __builtin_bit_cast(f16x8, fri);
      }

      acc[jt][0] = MFMA32(pa[0], bv[0][0], acc[jt][0]);
      acc[jt][1] = MFMA32(pa[0], bv[1][0], acc[jt][1]);
      acc[jt][0] = MFMA32(pa[1], bv[0][1], acc[jt][0]);
      acc[jt][1] = MFMA32(pa[1], bv[1][1], acc[jt][1]);
    }

    // stage write for next chunk
    if (t < 15) {
      *(f16x8a*)&etL[cur ^ 1][sei][sec] = sve;
      *(f16x8a*)&ecL[cur ^ 1][scc][sci] = svc;
    }
    __syncthreads();
  }

  // partial[iq][b][j][c] (out^T layout -> coalesced: lanes vary c)
  f16* pb = partial + (size_t)(iq * B + b) * HW * C;
  #pragma unroll
  for (int jt = 0; jt < 2; ++jt)
    #pragma unroll
    for (int cs = 0; cs < 2; ++cs)
      #pragma unroll
      for (int r = 0; r < 16; ++r) {
        int j = jbase + jt * 32 + (r & 3) + 8 * (r >> 2) + 4 * h;
        pb[(size_t)j * C + cs * 32 + l31] = (f16)acc[jt][cs][r];
      }
}

// ---------------- Kernel D: out[c][j] = x + sum_iq partial[iq][j][c] (transpose) ----
__global__ __launch_bounds__(256) void k_reduce(
    const f16* __restrict__ partial, const float* __restrict__ x, float* __restrict__ out)
{
  __shared__ float tile[64][65];
  const int blk = swz_blk();
  const int b = blk >> 6;
  const int j0 = (blk & 63) * 64;
  const int tid = threadIdx.x;
  const int jj = tid >> 2, cq = (tid & 3) * 16;

  float a0[16] = {};
  for (int iq = 0; iq < 8; ++iq) {
    const f16* p = partial + ((size_t)(iq * B + b) * HW + j0 + jj) * C + cq;
    f16x8 v0 = *(const f16x8*)p;
    f16x8 v1 = *(const f16x8*)(p + 8);
    #pragma unroll
    for (int e = 0; e < 8; ++e) { a0[e] += (float)v0[e]; a0[8 + e] += (float)v1[e]; }
  }
  #pragma unroll
  for (int e = 0; e < 16; ++e) tile[jj][cq + e] = a0[e];
  __syncthreads();

  const int c = tid >> 2, jq = (tid & 3) * 16;
  #pragma unroll
  for (int k = 0; k < 4; ++k) {
    size_t idx = ((size_t)b * C + c) * HW + j0 + jq + k * 4;
    float4 xv = *(const float4*)(x + idx);
    float4 ov;
    ov.x = tile[jq + k * 4 + 0][c] + xv.x;
    ov.y = tile[jq + k * 4 + 1][c] + xv.y;
    ov.z = tile[jq + k * 4 + 2][c] + xv.z;
    ov.w = tile[jq + k * 4 + 3][c] + xv.w;
    *(float4*)(out + idx) = ov;
  }
}

extern "C" void kernel_launch(void* const* d_in, const int* in_sizes, int n_in,
                              void* d_out, int out_size, void* d_ws, size_t ws_size,
                              hipStream_t stream) {
  const float* x = (const float*)d_in[0];
  const float* W = (const float*)d_in[1];
  const float* bconv = (const float*)d_in[2];
  float* out = (float*)d_out;

  f16* et16 = (f16*)d_ws;
  f16* ec16 = et16 + (size_t)B * HW * C;
  float* mbuf = (float*)(ec16 + (size_t)B * HW * C);
  float* lpartial = mbuf + (size_t)B * HW;               // [B][HW][4] f32
  f16* partial = (f16*)(lpartial + (size_t)B * HW * 4);  // 16 MB; ws total ~20.4 MB

  k_e<<<dim3(256), dim3(256), 0, stream>>>(x, W, bconv, et16, ec16, mbuf);
  k_stats<<<dim3(2048), dim3(256), 0, stream>>>(et16, mbuf, lpartial);
  k_out<<<dim3(512), dim3(256), 0, stream>>>(et16, ec16, mbuf, lpartial, partial);
  k_reduce<<<dim3(256), dim3(256), 0, stream>>>(partial, x, out);
}

// Round 13
// 61.010 us; speedup vs baseline: 1.4819x; 1.2059x over previous
//
#include <hip/hip_runtime.h>
#include <math.h>

#define B 4
#define C 64
#define HW 4096

typedef _Float16 f16;
typedef f16 f16x8 __attribute__((ext_vector_type(8)));
typedef f16 f16x4 __attribute__((ext_vector_type(4)));
typedef float f32x4 __attribute__((ext_vector_type(4)));
typedef float f32x16 __attribute__((ext_vector_type(16)));
typedef int i32x4 __attribute__((ext_vector_type(4)));
typedef f16x8 f16x8a __attribute__((aligned(8)));   // 8B-aligned vector loads

#define MFMA16(a,b,c) __builtin_amdgcn_mfma_f32_16x16x32_f16(a,b,c,0,0,0)
#define MFMA32(a,b,c) __builtin_amdgcn_mfma_f32_32x32x16_f16(a,b,c,0,0,0)

// ws layout (~20.4 MB):
//   et16    : [B][HW][C] f16  (e, i-major)           2 MB
//   ec16    : [B][C][HW] f16  (e, c-major)           2 MB
//   mbuf    : [B][HW] f32     (m~ = f16-rounded |e_i|^2)  64 KB
//   lpartial: [B][HW][4] f32  (split-j exp sums)     256 KB
//   partial : [8][B][HW][C] f16  (out^T per iq)      16 MB
//
// ALLOCATOR NOTES: plain __launch_bounds__(256) + amdgpu_waves_per_eu attr left
// k_stats pinned at 64 VGPR (spills, rounds 4/6/7/10). The __launch_bounds__(N, min_waves)
// SECOND-ARG form is the only knob that measurably raised the cap (R5 k_out: (512,2) -> 104).
// This round A/B-tests (256,2) on the 64-row k_stats.

// XCD-affine swizzles (8 XCDs x k contiguous logical blocks).
__device__ __forceinline__ int swz_blk()     { int r = blockIdx.x; return (r & 7) * 32  + (r >> 3); }
__device__ __forceinline__ int swz_blk512()  { int r = blockIdx.x; return (r & 7) * 64  + (r >> 3); }
__device__ __forceinline__ int swz_blk1024() { int r = blockIdx.x; return (r & 7) * 128 + (r >> 3); }

// ---------------- Kernel A: e = W @ x + bconv -> et16, ec16, mbuf -------------------
__global__ __launch_bounds__(256) void k_e(
    const float* __restrict__ x, const float* __restrict__ W,
    const float* __restrict__ bconv, f16* __restrict__ et, f16* __restrict__ ec,
    float* __restrict__ mbuf)
{
  __shared__ float Ws[64][65];
  __shared__ float xs[64][64];
  __shared__ __align__(16) f16 es[64][72];
  __shared__ float msp[4][64];
  const int blk = swz_blk();
  const int b = blk >> 6;
  const int i0 = (blk & 63) * 64;
  const int tid = threadIdx.x;

  for (int k = tid; k < 64 * 64; k += 256) Ws[k >> 6][k & 63] = W[k];
  for (int k = tid; k < 64 * 64; k += 256)
    xs[k >> 6][k & 63] = x[((size_t)b * C + (k >> 6)) * HW + i0 + (k & 63)];
  __syncthreads();

  const int o = tid & 63;
  const int ig = tid >> 6;
  float acc[16];
  float bv = bconv[o];
  #pragma unroll
  for (int k = 0; k < 16; ++k) acc[k] = bv;
  for (int c = 0; c < C; ++c) {
    float wv = Ws[o][c];
    #pragma unroll
    for (int k = 0; k < 16; ++k) acc[k] = fmaf(wv, xs[c][ig * 16 + k], acc[k]);
  }
  #pragma unroll
  for (int k = 0; k < 16; ++k) {
    int ii = ig * 16 + k;
    f16 v = (f16)acc[k];
    et[((size_t)b * HW + i0 + ii) * C + o] = v;
    es[o][ii] = v;
  }
  __syncthreads();

  // ec transpose (f16x4 vectorized stores)
  {
    const int ii4 = (tid & 15) * 4;
    const int ob = tid >> 4;
    #pragma unroll
    for (int k = 0; k < 4; ++k) {
      int oo = ob + 16 * k;
      f16x4 v = *(const f16x4*)&es[oo][ii4];
      *(f16x4*)&ec[((size_t)b * C + oo) * HW + i0 + ii4] = v;
    }
  }

  // m_i = |e_i|^2 (sum over channels, fp32 accum)
  const int ii = tid & 63, og = tid >> 6;
  {
    float s = 0.f;
    #pragma unroll
    for (int k = 0; k < 16; ++k) {
      float v = (float)es[og * 16 + k][ii];
      s = fmaf(v, v, s);
    }
    msp[og][ii] = s;
  }
  __syncthreads();
  if (tid < 64) {
    float mm = msp[0][tid] + msp[1][tid] + msp[2][tid] + msp[3][tid];
    // canonicalize the shift to f16 (k_out applies it through an f16 MFMA operand)
    mbuf[(size_t)b * HW + i0 + tid] = (float)(f16)mm;
  }
}

// ---------------- Kernel B: split-j softmax partials -------------------------------
// 1024 blocks = (b:4, ib:64 of 64 i-rows, jq:4 of 1024 j) x 256 thr (4 waves).
// __launch_bounds__(256, 2): min 2 waves/EU -> VGPR cap 128 -> ~95 live fits, no spill.
// 64 i-rows per block halves the redundant et B-sweep (270 -> 137 MB of L2 reads).
__global__ __launch_bounds__(256, 2)
void k_stats(const f16* __restrict__ et, const float* __restrict__ mbuf,
             float* __restrict__ lpartial)
{
  __shared__ float lpart[4][68];
  const int blk = swz_blk1024();
  const int b  = blk >> 8;
  const int ib = (blk >> 2) & 63;
  const int jq = blk & 3;
  const int i0 = ib * 64;
  const int tid = threadIdx.x;
  const int wv = tid >> 6;
  const int lane = tid & 63;
  const int lr = lane & 15, lg = lane >> 4;
  const f16* etb = et + (size_t)b * HW * C;

  // A-fragments: the block's 64 i-rows (4 subtiles x 2 K-chunks)
  f16x8 a[4][2];
  #pragma unroll
  for (int is = 0; is < 4; ++is)
    #pragma unroll
    for (int kc = 0; kc < 2; ++kc)
      a[is][kc] = *(const f16x8*)(etb + (size_t)(i0 + is * 16 + lr) * C + kc * 32 + lg * 8);

  // softmax shifts (f16-canonical, from k_e)
  f32x4 ms4[4];
  #pragma unroll
  for (int is = 0; is < 4; ++is)
    ms4[is] = *(const f32x4*)(mbuf + (size_t)b * HW + i0 + is * 16 + lg * 4);

  // sweep this block's 1024-j quarter: wave wv takes 32-j tiles wv+4t
  float lacc[4][4] = {};
  for (int t = 0; t < 8; ++t) {
    const int j0 = jq * 1024 + (wv + 4 * t) * 32;
    #pragma unroll
    for (int js = 0; js < 2; ++js) {
      f16x8 b0 = *(const f16x8*)(etb + (size_t)(j0 + js * 16 + lr) * C + lg * 8);
      f16x8 b1 = *(const f16x8*)(etb + (size_t)(j0 + js * 16 + lr) * C + 32 + lg * 8);
      #pragma unroll
      for (int is = 0; is < 4; ++is) {
        f32x4 z = {0.f, 0.f, 0.f, 0.f};
        f32x4 S = MFMA16(a[is][0], b0, z);
        S = MFMA16(a[is][1], b1, S);
        #pragma unroll
        for (int r = 0; r < 4; ++r) lacc[is][r] += __expf(S[r] - ms4[is][r]);
      }
    }
  }

  // reduce over the 16 j-columns held by lanes sharing lg
  #pragma unroll
  for (int m = 1; m < 16; m <<= 1)
    #pragma unroll
    for (int is = 0; is < 4; ++is)
      #pragma unroll
      for (int r = 0; r < 4; ++r) lacc[is][r] += __shfl_xor(lacc[is][r], m);

  if (lr == 0)
    #pragma unroll
    for (int is = 0; is < 4; ++is)
      #pragma unroll
      for (int r = 0; r < 4; ++r) lpart[wv][is * 16 + lg * 4 + r] = lacc[is][r];
  __syncthreads();

  if (tid < 64)
    lpartial[((size_t)b * HW + i0 + tid) * 4 + jq] =
        lpart[0][tid] + lpart[1][tid] + lpart[2][tid] + lpart[3][tid];
}

// ---------------- Kernel C: partial^T[iq] += P^T . e^T  (out^T = sum_i) -------------
// 512 blocks = (b:4, jb:16 of 256 j, iq:8 of 512 i). 256 thr = 4 waves, 64 j per wave.
#define ETS 68   // etL row stride (f16)
#define ECS 36   // ecL row stride
__global__ __launch_bounds__(256) __attribute__((amdgpu_waves_per_eu(2, 4)))
void k_out(
    const f16* __restrict__ et, const f16* __restrict__ ec,
    const float* __restrict__ mbuf, const float* __restrict__ lpartial,
    f16* __restrict__ partial)
{
  __shared__ __align__(16) f16 etL[2][32][ETS];    // [i][c]
  __shared__ __align__(16) f16 ecL[2][64][ECS];    // [c][i]
  __shared__ __align__(16) f16 maugAll[513][8];    // [m~, dhi, dlo, 0...]; row 512 = zeros
  const int blk = swz_blk512();
  const int b  = blk >> 7;
  const int jb = (blk >> 3) & 15;
  const int iq = blk & 7;
  const int tid = threadIdx.x;
  const int w = tid >> 6;          // 0..3
  const int lane = tid & 63;
  const int l31 = lane & 31;
  const int h = lane >> 5;
  const int jbase = jb * 256 + w * 64;   // wave owns 64 j (2 jt tiles of 32)
  const int ibase = iq * 512;

  const f16* etb = et + (size_t)b * HW * C;
  const f16* ecb = ec + (size_t)b * C * HW;

  // per-i softmax constants for the block's 512 i (2 rows per thread)
  #pragma unroll
  for (int rr = 0; rr < 2; ++rr) {
    int i = tid + rr * 256;
    float m = mbuf[(size_t)b * HW + ibase + i];
    f32x4 lp = *(const f32x4*)&lpartial[((size_t)b * HW + ibase + i) * 4];
    float l = lp[0] + lp[1] + lp[2] + lp[3];
    float d = __logf(l);
    f16 dh = (f16)d;
    f16 dl = (f16)(d - (float)dh);
    f16x8 row = {};
    row[0] = (f16)m; row[1] = dh; row[2] = dl;
    *(f16x8*)&maugAll[i][0] = row;
  }
  if (tid == 0) { f16x8 zz = {}; *(f16x8*)&maugAll[512][0] = zz; }

  // constant aug B-fragment: -1 at k_local 0,1,2 (h=0 lanes), 0 elsewhere
  f16x8 baug = {};
  if (h == 0) { baug[0] = (f16)-1.f; baug[1] = (f16)-1.f; baug[2] = (f16)-1.f; }

  // score B fragments (regs, fixed): 2 jt tiles x 4 K-chunks of 16 c
  f16x8 bj[2][4];
  #pragma unroll
  for (int jt = 0; jt < 2; ++jt)
    #pragma unroll
    for (int kc = 0; kc < 4; ++kc)
      bj[jt][kc] = *(const f16x8*)(etb + (size_t)(jbase + jt * 32 + l31) * C + kc * 16 + h * 8);

  f32x16 acc[2][2] = {};   // [jt][cs] of out^T (m=j, n=c)

  // staging: EVERY thread stages one et vector and one ec vector per chunk
  const int sei = tid >> 3;          // et row 0..31
  const int sec = (tid & 7) * 8;     // et col
  const int scc = tid >> 2;          // ec row (c) 0..63
  const int sci = (tid & 3) * 8;     // ec col (i)

  // prologue: stage chunk 0
  *(f16x8a*)&etL[0][sei][sec] = *(const f16x8*)(etb + (size_t)(ibase + sei) * C + sec);
  *(f16x8a*)&ecL[0][scc][sci] = *(const f16x8*)(ecb + (size_t)scc * HW + ibase + sci);
  __syncthreads();

  for (int t = 0; t < 16; ++t) {
    const int cur = t & 1;
    const int i0c = ibase + t * 32;

    // issue next chunk's global loads early
    f16x8 sve, svc;
    if (t < 15) {
      sve = *(const f16x8*)(etb + (size_t)(i0c + 32 + sei) * C + sec);
      svc = *(const f16x8*)(ecb + (size_t)scc * HW + (i0c + 32) + sci);
    }

    // PV B fragments (e^T): B[k=i][n=c] from ecL
    f16x8 bv[2][2];
    #pragma unroll
    for (int cs = 0; cs < 2; ++cs)
      #pragma unroll
      for (int kf = 0; kf < 2; ++kf)
        bv[cs][kf] = *(const f16x8a*)&ecL[cur][cs * 32 + l31][kf * 16 + h * 8];

    // score A fragments: A[m=i][k=c] from etL, + aug fragment
    f16x8 af[4];
    #pragma unroll
    for (int kc = 0; kc < 4; ++kc)
      af[kc] = *(const f16x8a*)&etL[cur][l31][kc * 16 + h * 8];
    f16x8 aaug = *(const f16x8*)&maugAll[h ? 512 : (t * 32 + l31)][0];

    #pragma unroll
    for (int jt = 0; jt < 2; ++jt) {
      // S' = e_i . e_j - m~_i - ln(l_i)
      f32x16 z = {};
      f32x16 S = MFMA32(af[0], bj[jt][0], z);
      S = MFMA32(af[1], bj[jt][1], S);
      S = MFMA32(af[2], bj[jt][2], S);
      S = MFMA32(af[3], bj[jt][3], S);
      S = MFMA32(aaug, baug, S);

      // P = exp(S'); repack to PV A-frag (lane=j, k=i) via pkrtz + permlane32_swap
      f16x8 pa[2];
      #pragma unroll
      for (int kf = 0; kf < 2; ++kf) {
        int A0 = __builtin_bit_cast(int, __builtin_amdgcn_cvt_pkrtz(__expf(S[kf * 8 + 0]), __expf(S[kf * 8 + 1])));
        int A1 = __builtin_bit_cast(int, __builtin_amdgcn_cvt_pkrtz(__expf(S[kf * 8 + 2]), __expf(S[kf * 8 + 3])));
        int B0 = __builtin_bit_cast(int, __builtin_amdgcn_cvt_pkrtz(__expf(S[kf * 8 + 4]), __expf(S[kf * 8 + 5])));
        int B1 = __builtin_bit_cast(int, __builtin_amdgcn_cvt_pkrtz(__expf(S[kf * 8 + 6]), __expf(S[kf * 8 + 7])));
        // HW semantic: vdst.hi <-> vsrc.lo. vdst=A (low rows), vsrc=B (high rows).
        asm volatile("v_permlane32_swap_b32 %0, %1" : "+v"(A0), "+v"(B0));
        asm volatile("v_permlane32_swap_b32 %0, %1" : "+v"(A1), "+v"(B1));
        i32x4 fri = {A0, A1, B0, B1};
        pa[kf] = __builtin_bit_cast(f16x8, fri);
      }

      acc[jt][0] = MFMA32(pa[0], bv[0][0], acc[jt][0]);
      acc[jt][1] = MFMA32(pa[0], bv[1][0], acc[jt][1]);
      acc[jt][0] = MFMA32(pa[1], bv[0][1], acc[jt][0]);
      acc[jt][1] = MFMA32(pa[1], bv[1][1], acc[jt][1]);
    }

    // stage write for next chunk
    if (t < 15) {
      *(f16x8a*)&etL[cur ^ 1][sei][sec] = sve;
      *(f16x8a*)&ecL[cur ^ 1][scc][sci] = svc;
    }
    __syncthreads();
  }

  // partial[iq][b][j][c] (out^T layout -> coalesced: lanes vary c)
  f16* pb = partial + (size_t)(iq * B + b) * HW * C;
  #pragma unroll
  for (int jt = 0; jt < 2; ++jt)
    #pragma unroll
    for (int cs = 0; cs < 2; ++cs)
      #pragma unroll
      for (int r = 0; r < 16; ++r) {
        int j = jbase + jt * 32 + (r & 3) + 8 * (r >> 2) + 4 * h;
        pb[(size_t)j * C + cs * 32 + l31] = (f16)acc[jt][cs][r];
      }
}

// ---------------- Kernel D: out[c][j] = x + sum_iq partial[iq][j][c] (transpose) ----
// 512 blocks = (b:4, 128 j-tiles of 32) x 256 thr -> 2 blocks/CU (was 1) for MLP.
__global__ __launch_bounds__(256) void k_reduce(
    const f16* __restrict__ partial, const float* __restrict__ x, float* __restrict__ out)
{
  __shared__ float tile[32][65];
  const int blk = swz_blk512();
  const int b = blk >> 7;
  const int j0 = (blk & 127) * 32;
  const int tid = threadIdx.x;

  // accumulate: thread handles row jj = tid/8, col chunk cq = (tid%8)*8
  const int jj = tid >> 3, cq = (tid & 7) * 8;
  float a0[8] = {};
  for (int iq = 0; iq < 8; ++iq) {
    const f16* p = partial + ((size_t)(iq * B + b) * HW + j0 + jj) * C + cq;
    f16x8 v = *(const f16x8*)p;
    #pragma unroll
    for (int e = 0; e < 8; ++e) a0[e] += (float)v[e];
  }
  #pragma unroll
  for (int e = 0; e < 8; ++e) tile[jj][cq + e] = a0[e];
  __syncthreads();

  // write: thread handles 8 channels (cg) x 1 j (jl); lanes vary jl -> coalesced
  const int jl = tid & 31, cg = tid >> 5;
  #pragma unroll
  for (int k = 0; k < 8; ++k) {
    int c = cg * 8 + k;
    size_t idx = ((size_t)b * C + c) * HW + j0 + jl;
    out[idx] = tile[jl][c] + x[idx];
  }
}

extern "C" void kernel_launch(void* const* d_in, const int* in_sizes, int n_in,
                              void* d_out, int out_size, void* d_ws, size_t ws_size,
                              hipStream_t stream) {
  const float* x = (const float*)d_in[0];
  const float* W = (const float*)d_in[1];
  const float* bconv = (const float*)d_in[2];
  float* out = (float*)d_out;

  f16* et16 = (f16*)d_ws;
  f16* ec16 = et16 + (size_t)B * HW * C;
  float* mbuf = (float*)(ec16 + (size_t)B * HW * C);
  float* lpartial = mbuf + (size_t)B * HW;               // [B][HW][4] f32
  f16* partial = (f16*)(lpartial + (size_t)B * HW * 4);  // 16 MB; ws total ~20.4 MB

  k_e<<<dim3(256), dim3(256), 0, stream>>>(x, W, bconv, et16, ec16, mbuf);
  k_stats<<<dim3(1024), dim3(256), 0, stream>>>(et16, mbuf, lpartial);
  k_out<<<dim3(512), dim3(256), 0, stream>>>(et16, ec16, mbuf, lpartial, partial);
  k_reduce<<<dim3(512), dim3(256), 0, stream>>>(partial, x, out);
}

// Round 14
// 60.133 us; speedup vs baseline: 1.5035x; 1.0146x over previous
//
#include <hip/hip_runtime.h>
#include <math.h>

#define B 4
#define C 64
#define HW 4096

typedef _Float16 f16;
typedef f16 f16x8 __attribute__((ext_vector_type(8)));
typedef f16 f16x4 __attribute__((ext_vector_type(4)));
typedef float f32x4 __attribute__((ext_vector_type(4)));
typedef float f32x16 __attribute__((ext_vector_type(16)));
typedef int i32x4 __attribute__((ext_vector_type(4)));

#define MFMA16(a,b,c) __builtin_amdgcn_mfma_f32_16x16x32_f16(a,b,c,0,0,0)
#define MFMA32(a,b,c) __builtin_amdgcn_mfma_f32_32x32x16_f16(a,b,c,0,0,0)

// ws layout (~20.4 MB):
//   et16    : [B][HW][C] f16  (e, i-major)           2 MB
//   ec16    : [B][C][HW] f16  (e, c-major)           2 MB
//   mbuf    : [B][HW] f32     (m~ = f16-rounded |e_i|^2)  64 KB
//   lpartial: [B][HW][4] f32  (split-j exp sums)     256 KB
//   partial : [8][B][HW][C] f16  (out^T per iq)      16 MB
//
// ALLOCATOR NOTES: plain __launch_bounds__(256) and the amdgpu_waves_per_eu attr
// left k_stats pinned at 64 VGPR (spills, R4/6/7/10). __launch_bounds__(N, min_waves)
// (second-arg form) is the knob that works (R13 A/B: 64-row k_stats stopped spilling).
//
// LDS ALIGNMENT NOTE (this round): row strides must be 16B multiples or f16x8
// accesses split into 2x ds_read_b64. ETS=72/ECS=40 are 16B-multiple AND
// bank-conflict-free for our read/write patterns (verified by bank algebra).

// XCD-affine swizzles (8 XCDs x k contiguous logical blocks).
__device__ __forceinline__ int swz_blk()     { int r = blockIdx.x; return (r & 7) * 32  + (r >> 3); }
__device__ __forceinline__ int swz_blk512()  { int r = blockIdx.x; return (r & 7) * 64  + (r >> 3); }
__device__ __forceinline__ int swz_blk1024() { int r = blockIdx.x; return (r & 7) * 128 + (r >> 3); }

// ---------------- Kernel A: e = W @ x + bconv -> et16, ec16, mbuf -------------------
__global__ __launch_bounds__(256) void k_e(
    const float* __restrict__ x, const float* __restrict__ W,
    const float* __restrict__ bconv, f16* __restrict__ et, f16* __restrict__ ec,
    float* __restrict__ mbuf)
{
  __shared__ float Ws[64][65];
  __shared__ __align__(16) float xs[64][64];
  __shared__ __align__(16) f16 es[64][72];
  __shared__ float msp[4][64];
  const int blk = swz_blk();
  const int b = blk >> 6;
  const int i0 = (blk & 63) * 64;
  const int tid = threadIdx.x;

  for (int k = tid; k < 64 * 64; k += 256) Ws[k >> 6][k & 63] = W[k];
  // x staging: float4 global loads (1024 float4s / 256 threads = 4 each)
  {
    const float* xb = x + (size_t)b * C * HW + i0;   // row c starts at xb + c*HW
    #pragma unroll
    for (int it = 0; it < 4; ++it) {
      int idx = tid + it * 256;            // float4 index: row = idx>>4, col4 = idx&15
      int r = idx >> 4, c4 = (idx & 15) * 4;
      f32x4 v = *(const f32x4*)(xb + (size_t)r * HW + c4);
      *(f32x4*)&xs[r][c4] = v;
    }
  }
  __syncthreads();

  const int o = tid & 63;
  const int ig = tid >> 6;
  float acc[16];
  float bv = bconv[o];
  #pragma unroll
  for (int k = 0; k < 16; ++k) acc[k] = bv;
  for (int c = 0; c < C; ++c) {
    float wv = Ws[o][c];
    #pragma unroll
    for (int k = 0; k < 16; ++k) acc[k] = fmaf(wv, xs[c][ig * 16 + k], acc[k]);
  }
  #pragma unroll
  for (int k = 0; k < 16; ++k) {
    int ii = ig * 16 + k;
    f16 v = (f16)acc[k];
    et[((size_t)b * HW + i0 + ii) * C + o] = v;
    es[o][ii] = v;
  }
  __syncthreads();

  // ec transpose (f16x4 vectorized stores)
  {
    const int ii4 = (tid & 15) * 4;
    const int ob = tid >> 4;
    #pragma unroll
    for (int k = 0; k < 4; ++k) {
      int oo = ob + 16 * k;
      f16x4 v = *(const f16x4*)&es[oo][ii4];
      *(f16x4*)&ec[((size_t)b * C + oo) * HW + i0 + ii4] = v;
    }
  }

  // m_i = |e_i|^2 (sum over channels, fp32 accum)
  const int ii = tid & 63, og = tid >> 6;
  {
    float s = 0.f;
    #pragma unroll
    for (int k = 0; k < 16; ++k) {
      float v = (float)es[og * 16 + k][ii];
      s = fmaf(v, v, s);
    }
    msp[og][ii] = s;
  }
  __syncthreads();
  if (tid < 64) {
    float mm = msp[0][tid] + msp[1][tid] + msp[2][tid] + msp[3][tid];
    // canonicalize the shift to f16 (k_out applies it through an f16 MFMA operand)
    mbuf[(size_t)b * HW + i0 + tid] = (float)(f16)mm;
  }
}

// ---------------- Kernel B: split-j softmax partials -------------------------------
// 1024 blocks = (b:4, ib:64 of 64 i-rows, jq:4 of 1024 j) x 256 thr (4 waves).
// __launch_bounds__(256, 2): VGPR cap 128 -> ~95 live fits, no spill (R13-proven).
__global__ __launch_bounds__(256, 2)
void k_stats(const f16* __restrict__ et, const float* __restrict__ mbuf,
             float* __restrict__ lpartial)
{
  __shared__ float lpart[4][68];
  const int blk = swz_blk1024();
  const int b  = blk >> 8;
  const int ib = (blk >> 2) & 63;
  const int jq = blk & 3;
  const int i0 = ib * 64;
  const int tid = threadIdx.x;
  const int wv = tid >> 6;
  const int lane = tid & 63;
  const int lr = lane & 15, lg = lane >> 4;
  const f16* etb = et + (size_t)b * HW * C;

  // A-fragments: the block's 64 i-rows (4 subtiles x 2 K-chunks)
  f16x8 a[4][2];
  #pragma unroll
  for (int is = 0; is < 4; ++is)
    #pragma unroll
    for (int kc = 0; kc < 2; ++kc)
      a[is][kc] = *(const f16x8*)(etb + (size_t)(i0 + is * 16 + lr) * C + kc * 32 + lg * 8);

  // softmax shifts (f16-canonical, from k_e)
  f32x4 ms4[4];
  #pragma unroll
  for (int is = 0; is < 4; ++is)
    ms4[is] = *(const f32x4*)(mbuf + (size_t)b * HW + i0 + is * 16 + lg * 4);

  // sweep this block's 1024-j quarter: wave wv takes 32-j tiles wv+4t
  float lacc[4][4] = {};
  for (int t = 0; t < 8; ++t) {
    const int j0 = jq * 1024 + (wv + 4 * t) * 32;
    #pragma unroll
    for (int js = 0; js < 2; ++js) {
      f16x8 b0 = *(const f16x8*)(etb + (size_t)(j0 + js * 16 + lr) * C + lg * 8);
      f16x8 b1 = *(const f16x8*)(etb + (size_t)(j0 + js * 16 + lr) * C + 32 + lg * 8);
      #pragma unroll
      for (int is = 0; is < 4; ++is) {
        f32x4 z = {0.f, 0.f, 0.f, 0.f};
        f32x4 S = MFMA16(a[is][0], b0, z);
        S = MFMA16(a[is][1], b1, S);
        #pragma unroll
        for (int r = 0; r < 4; ++r) lacc[is][r] += __expf(S[r] - ms4[is][r]);
      }
    }
  }

  // reduce over the 16 j-columns held by lanes sharing lg
  #pragma unroll
  for (int m = 1; m < 16; m <<= 1)
    #pragma unroll
    for (int is = 0; is < 4; ++is)
      #pragma unroll
      for (int r = 0; r < 4; ++r) lacc[is][r] += __shfl_xor(lacc[is][r], m);

  if (lr == 0)
    #pragma unroll
    for (int is = 0; is < 4; ++is)
      #pragma unroll
      for (int r = 0; r < 4; ++r) lpart[wv][is * 16 + lg * 4 + r] = lacc[is][r];
  __syncthreads();

  if (tid < 64)
    lpartial[((size_t)b * HW + i0 + tid) * 4 + jq] =
        lpart[0][tid] + lpart[1][tid] + lpart[2][tid] + lpart[3][tid];
}

// ---------------- Kernel C: partial^T[iq] += P^T . e^T  (out^T = sum_i) -------------
// 512 blocks = (b:4, jb:16 of 256 j, iq:8 of 512 i). 256 thr = 4 waves, 64 j per wave.
// ETS=72 (144B) / ECS=40 (80B): 16B-aligned rows -> single ds_read_b128 per fragment,
// bank-conflict-free (windows cover all 32 banks per phase).
#define ETS 72   // etL row stride (f16)
#define ECS 40   // ecL row stride
__global__ __launch_bounds__(256) __attribute__((amdgpu_waves_per_eu(2, 4)))
void k_out(
    const f16* __restrict__ et, const f16* __restrict__ ec,
    const float* __restrict__ mbuf, const float* __restrict__ lpartial,
    f16* __restrict__ partial)
{
  __shared__ __align__(16) f16 etL[2][32][ETS];    // [i][c]
  __shared__ __align__(16) f16 ecL[2][64][ECS];    // [c][i]
  __shared__ __align__(16) f16 maugAll[513][8];    // [m~, dhi, dlo, 0...]; row 512 = zeros
  const int blk = swz_blk512();
  const int b  = blk >> 7;
  const int jb = (blk >> 3) & 15;
  const int iq = blk & 7;
  const int tid = threadIdx.x;
  const int w = tid >> 6;          // 0..3
  const int lane = tid & 63;
  const int l31 = lane & 31;
  const int h = lane >> 5;
  const int jbase = jb * 256 + w * 64;   // wave owns 64 j (2 jt tiles of 32)
  const int ibase = iq * 512;

  const f16* etb = et + (size_t)b * HW * C;
  const f16* ecb = ec + (size_t)b * C * HW;

  // per-i softmax constants for the block's 512 i (2 rows per thread)
  #pragma unroll
  for (int rr = 0; rr < 2; ++rr) {
    int i = tid + rr * 256;
    float m = mbuf[(size_t)b * HW + ibase + i];
    f32x4 lp = *(const f32x4*)&lpartial[((size_t)b * HW + ibase + i) * 4];
    float l = lp[0] + lp[1] + lp[2] + lp[3];
    float d = __logf(l);
    f16 dh = (f16)d;
    f16 dl = (f16)(d - (float)dh);
    f16x8 row = {};
    row[0] = (f16)m; row[1] = dh; row[2] = dl;
    *(f16x8*)&maugAll[i][0] = row;
  }
  if (tid == 0) { f16x8 zz = {}; *(f16x8*)&maugAll[512][0] = zz; }

  // constant aug B-fragment: -1 at k_local 0,1,2 (h=0 lanes), 0 elsewhere
  f16x8 baug = {};
  if (h == 0) { baug[0] = (f16)-1.f; baug[1] = (f16)-1.f; baug[2] = (f16)-1.f; }

  // score B fragments (regs, fixed): 2 jt tiles x 4 K-chunks of 16 c
  f16x8 bj[2][4];
  #pragma unroll
  for (int jt = 0; jt < 2; ++jt)
    #pragma unroll
    for (int kc = 0; kc < 4; ++kc)
      bj[jt][kc] = *(const f16x8*)(etb + (size_t)(jbase + jt * 32 + l31) * C + kc * 16 + h * 8);

  f32x16 acc[2][2] = {};   // [jt][cs] of out^T (m=j, n=c)

  // staging: EVERY thread stages one et vector and one ec vector per chunk
  const int sei = tid >> 3;          // et row 0..31
  const int sec = (tid & 7) * 8;     // et col
  const int scc = tid >> 2;          // ec row (c) 0..63
  const int sci = (tid & 3) * 8;     // ec col (i)

  // prologue: stage chunk 0
  *(f16x8*)&etL[0][sei][sec] = *(const f16x8*)(etb + (size_t)(ibase + sei) * C + sec);
  *(f16x8*)&ecL[0][scc][sci] = *(const f16x8*)(ecb + (size_t)scc * HW + ibase + sci);
  __syncthreads();

  for (int t = 0; t < 16; ++t) {
    const int cur = t & 1;
    const int i0c = ibase + t * 32;

    // issue next chunk's global loads early
    f16x8 sve, svc;
    if (t < 15) {
      sve = *(const f16x8*)(etb + (size_t)(i0c + 32 + sei) * C + sec);
      svc = *(const f16x8*)(ecb + (size_t)scc * HW + (i0c + 32) + sci);
    }

    // PV B fragments (e^T): B[k=i][n=c] from ecL
    f16x8 bv[2][2];
    #pragma unroll
    for (int cs = 0; cs < 2; ++cs)
      #pragma unroll
      for (int kf = 0; kf < 2; ++kf)
        bv[cs][kf] = *(const f16x8*)&ecL[cur][cs * 32 + l31][kf * 16 + h * 8];

    // score A fragments: A[m=i][k=c] from etL, + aug fragment
    f16x8 af[4];
    #pragma unroll
    for (int kc = 0; kc < 4; ++kc)
      af[kc] = *(const f16x8*)&etL[cur][l31][kc * 16 + h * 8];
    f16x8 aaug = *(const f16x8*)&maugAll[h ? 512 : (t * 32 + l31)][0];

    #pragma unroll
    for (int jt = 0; jt < 2; ++jt) {
      // S' = e_i . e_j - m~_i - ln(l_i)
      f32x16 z = {};
      f32x16 S = MFMA32(af[0], bj[jt][0], z);
      S = MFMA32(af[1], bj[jt][1], S);
      S = MFMA32(af[2], bj[jt][2], S);
      S = MFMA32(af[3], bj[jt][3], S);
      S = MFMA32(aaug, baug, S);

      // P = exp(S'); repack to PV A-frag (lane=j, k=i) via pkrtz + permlane32_swap
      f16x8 pa[2];
      #pragma unroll
      for (int kf = 0; kf < 2; ++kf) {
        int A0 = __builtin_bit_cast(int, __builtin_amdgcn_cvt_pkrtz(__expf(S[kf * 8 + 0]), __expf(S[kf * 8 + 1])));
        int A1 = __builtin_bit_cast(int, __builtin_amdgcn_cvt_pkrtz(__expf(S[kf * 8 + 2]), __expf(S[kf * 8 + 3])));
        int B0 = __builtin_bit_cast(int, __builtin_amdgcn_cvt_pkrtz(__expf(S[kf * 8 + 4]), __expf(S[kf * 8 + 5])));
        int B1 = __builtin_bit_cast(int, __builtin_amdgcn_cvt_pkrtz(__expf(S[kf * 8 + 6]), __expf(S[kf * 8 + 7])));
        // HW semantic: vdst.hi <-> vsrc.lo. vdst=A (low rows), vsrc=B (high rows).
        asm volatile("v_permlane32_swap_b32 %0, %1" : "+v"(A0), "+v"(B0));
        asm volatile("v_permlane32_swap_b32 %0, %1" : "+v"(A1), "+v"(B1));
        i32x4 fri = {A0, A1, B0, B1};
        pa[kf] = __builtin_bit_cast(f16x8, fri);
      }

      acc[jt][0] = MFMA32(pa[0], bv[0][0], acc[jt][0]);
      acc[jt][1] = MFMA32(pa[0], bv[1][0], acc[jt][1]);
      acc[jt][0] = MFMA32(pa[1], bv[0][1], acc[jt][0]);
      acc[jt][1] = MFMA32(pa[1], bv[1][1], acc[jt][1]);
    }

    // stage write for next chunk
    if (t < 15) {
      *(f16x8*)&etL[cur ^ 1][sei][sec] = sve;
      *(f16x8*)&ecL[cur ^ 1][scc][sci] = svc;
    }
    __syncthreads();
  }

  // partial[iq][b][j][c] (out^T layout -> coalesced: lanes vary c)
  f16* pb = partial + (size_t)(iq * B + b) * HW * C;
  #pragma unroll
  for (int jt = 0; jt < 2; ++jt)
    #pragma unroll
    for (int cs = 0; cs < 2; ++cs)
      #pragma unroll
      for (int r = 0; r < 16; ++r) {
        int j = jbase + jt * 32 + (r & 3) + 8 * (r >> 2) + 4 * h;
        pb[(size_t)j * C + cs * 32 + l31] = (f16)acc[jt][cs][r];
      }
}

// ---------------- Kernel D: out[c][j] = x + sum_iq partial[iq][j][c] (transpose) ----
// 512 blocks = (b:4, 128 j-tiles of 32) x 256 thr -> 2 blocks/CU for MLP.
__global__ __launch_bounds__(256) void k_reduce(
    const f16* __restrict__ partial, const float* __restrict__ x, float* __restrict__ out)
{
  __shared__ float tile[32][65];
  const int blk = swz_blk512();
  const int b = blk >> 7;
  const int j0 = (blk & 127) * 32;
  const int tid = threadIdx.x;

  // accumulate: thread handles row jj = tid/8, col chunk cq = (tid%8)*8
  const int jj = tid >> 3, cq = (tid & 7) * 8;
  float a0[8] = {};
  for (int iq = 0; iq < 8; ++iq) {
    const f16* p = partial + ((size_t)(iq * B + b) * HW + j0 + jj) * C + cq;
    f16x8 v = *(const f16x8*)p;
    #pragma unroll
    for (int e = 0; e < 8; ++e) a0[e] += (float)v[e];
  }
  #pragma unroll
  for (int e = 0; e < 8; ++e) tile[jj][cq + e] = a0[e];
  __syncthreads();

  // write: thread handles 8 channels (cg) x 1 j (jl); lanes vary jl -> coalesced
  const int jl = tid & 31, cg = tid >> 5;
  #pragma unroll
  for (int k = 0; k < 8; ++k) {
    int c = cg * 8 + k;
    size_t idx = ((size_t)b * C + c) * HW + j0 + jl;
    out[idx] = tile[jl][c] + x[idx];
  }
}

extern "C" void kernel_launch(void* const* d_in, const int* in_sizes, int n_in,
                              void* d_out, int out_size, void* d_ws, size_t ws_size,
                              hipStream_t stream) {
  const float* x = (const float*)d_in[0];
  const float* W = (const float*)d_in[1];
  const float* bconv = (const float*)d_in[2];
  float* out = (float*)d_out;

  f16* et16 = (f16*)d_ws;
  f16* ec16 = et16 + (size_t)B * HW * C;
  float* mbuf = (float*)(ec16 + (size_t)B * HW * C);
  float* lpartial = mbuf + (size_t)B * HW;               // [B][HW][4] f32
  f16* partial = (f16*)(lpartial + (size_t)B * HW * 4);  // 16 MB; ws total ~20.4 MB

  k_e<<<dim3(256), dim3(256), 0, stream>>>(x, W, bconv, et16, ec16, mbuf);
  k_stats<<<dim3(1024), dim3(256), 0, stream>>>(et16, mbuf, lpartial);
  k_out<<<dim3(512), dim3(256), 0, stream>>>(et16, ec16, mbuf, lpartial, partial);
  k_reduce<<<dim3(512), dim3(256), 0, stream>>>(partial, x, out);
}

// Round 16
// 59.563 us; speedup vs baseline: 1.5179x; 1.0096x over previous
//
#include <hip/hip_runtime.h>
#include <math.h>

#define B 4
#define C 64
#define HW 4096

typedef _Float16 f16;
typedef f16 f16x8 __attribute__((ext_vector_type(8)));
typedef f16 f16x4 __attribute__((ext_vector_type(4)));
typedef float f32x4 __attribute__((ext_vector_type(4)));
typedef float f32x16 __attribute__((ext_vector_type(16)));
typedef int i32x4 __attribute__((ext_vector_type(4)));

#define MFMA16(a,b,c) __builtin_amdgcn_mfma_f32_16x16x32_f16(a,b,c,0,0,0)
#define MFMA32(a,b,c) __builtin_amdgcn_mfma_f32_32x32x16_f16(a,b,c,0,0,0)

// ws layout (~20.4 MB):
//   et16    : [B][HW][C] f16  (e, i-major)           2 MB
//   ec16    : [B][C][HW] f16  (e, c-major)           2 MB
//   mbuf    : [B][HW] f32     (m~ = f16-rounded |e_i|^2)  64 KB
//   lpartial: [B][HW][4] f32  (split-j exp sums)     256 KB
//   partial : [8][B][HW][C] f16  (out^T per iq)      16 MB
//
// ALLOCATOR NOTES: plain __launch_bounds__(256) and the amdgpu_waves_per_eu attr
// left k_stats pinned at 64 VGPR (spills, R4/6/7/10). __launch_bounds__(N, min_waves)
// (second-arg form) is the knob that works (R13 A/B).
// LDS row strides must be 16B multiples or f16x8 accesses split into 2x ds_read_b64.
// FUSION NOTE (R15): cross-block threadfence/atomic reduction of partial FAILED
// (absmax 4.24, stale partials across blocks). Do not re-attempt without a
// hardware-verified visibility protocol; keep the separate k_reduce dispatch.

// XCD-affine swizzles (8 XCDs x k contiguous logical blocks).
__device__ __forceinline__ int swz_blk()     { int r = blockIdx.x; return (r & 7) * 32  + (r >> 3); }
__device__ __forceinline__ int swz_blk512()  { int r = blockIdx.x; return (r & 7) * 64  + (r >> 3); }
__device__ __forceinline__ int swz_blk1024() { int r = blockIdx.x; return (r & 7) * 128 + (r >> 3); }

// ---------------- Kernel A: e = W @ x + bconv -> et16, ec16, mbuf -------------------
__global__ __launch_bounds__(256) void k_e(
    const float* __restrict__ x, const float* __restrict__ W,
    const float* __restrict__ bconv, f16* __restrict__ et, f16* __restrict__ ec,
    float* __restrict__ mbuf)
{
  __shared__ float Ws[64][65];
  __shared__ __align__(16) float xs[64][64];
  __shared__ __align__(16) f16 es[64][72];
  __shared__ float msp[4][64];
  const int blk = swz_blk();
  const int b = blk >> 6;
  const int i0 = (blk & 63) * 64;
  const int tid = threadIdx.x;

  for (int k = tid; k < 64 * 64; k += 256) Ws[k >> 6][k & 63] = W[k];
  // x staging: float4 global loads
  {
    const float* xb = x + (size_t)b * C * HW + i0;
    #pragma unroll
    for (int it = 0; it < 4; ++it) {
      int idx = tid + it * 256;
      int r = idx >> 4, c4 = (idx & 15) * 4;
      f32x4 v = *(const f32x4*)(xb + (size_t)r * HW + c4);
      *(f32x4*)&xs[r][c4] = v;
    }
  }
  __syncthreads();

  const int o = tid & 63;
  const int ig = tid >> 6;
  float acc[16];
  float bv = bconv[o];
  #pragma unroll
  for (int k = 0; k < 16; ++k) acc[k] = bv;
  for (int c = 0; c < C; ++c) {
    float wv = Ws[o][c];
    #pragma unroll
    for (int k = 0; k < 16; ++k) acc[k] = fmaf(wv, xs[c][ig * 16 + k], acc[k]);
  }
  #pragma unroll
  for (int k = 0; k < 16; ++k) {
    int ii = ig * 16 + k;
    f16 v = (f16)acc[k];
    et[((size_t)b * HW + i0 + ii) * C + o] = v;
    es[o][ii] = v;
  }
  __syncthreads();

  // ec transpose (f16x4 vectorized stores)
  {
    const int ii4 = (tid & 15) * 4;
    const int ob = tid >> 4;
    #pragma unroll
    for (int k = 0; k < 4; ++k) {
      int oo = ob + 16 * k;
      f16x4 v = *(const f16x4*)&es[oo][ii4];
      *(f16x4*)&ec[((size_t)b * C + oo) * HW + i0 + ii4] = v;
    }
  }

  // m_i = |e_i|^2 (sum over channels, fp32 accum)
  const int ii = tid & 63, og = tid >> 6;
  {
    float s = 0.f;
    #pragma unroll
    for (int k = 0; k < 16; ++k) {
      float v = (float)es[og * 16 + k][ii];
      s = fmaf(v, v, s);
    }
    msp[og][ii] = s;
  }
  __syncthreads();
  if (tid < 64) {
    float mm = msp[0][tid] + msp[1][tid] + msp[2][tid] + msp[3][tid];
    mbuf[(size_t)b * HW + i0 + tid] = (float)(f16)mm;   // f16-canonical shift
  }
}

// ---------------- Kernel B: split-j softmax partials -------------------------------
// 1024 blocks = (b:4, ib:64 of 64 i-rows, jq:4 of 1024 j) x 256 thr (4 waves).
__global__ __launch_bounds__(256, 2)
void k_stats(const f16* __restrict__ et, const float* __restrict__ mbuf,
             float* __restrict__ lpartial)
{
  __shared__ float lpart[4][68];
  const int blk = swz_blk1024();
  const int b  = blk >> 8;
  const int ib = (blk >> 2) & 63;
  const int jq = blk & 3;
  const int i0 = ib * 64;
  const int tid = threadIdx.x;
  const int wv = tid >> 6;
  const int lane = tid & 63;
  const int lr = lane & 15, lg = lane >> 4;
  const f16* etb = et + (size_t)b * HW * C;

  f16x8 a[4][2];
  #pragma unroll
  for (int is = 0; is < 4; ++is)
    #pragma unroll
    for (int kc = 0; kc < 2; ++kc)
      a[is][kc] = *(const f16x8*)(etb + (size_t)(i0 + is * 16 + lr) * C + kc * 32 + lg * 8);

  f32x4 ms4[4];
  #pragma unroll
  for (int is = 0; is < 4; ++is)
    ms4[is] = *(const f32x4*)(mbuf + (size_t)b * HW + i0 + is * 16 + lg * 4);

  float lacc[4][4] = {};
  for (int t = 0; t < 8; ++t) {
    const int j0 = jq * 1024 + (wv + 4 * t) * 32;
    #pragma unroll
    for (int js = 0; js < 2; ++js) {
      f16x8 b0 = *(const f16x8*)(etb + (size_t)(j0 + js * 16 + lr) * C + lg * 8);
      f16x8 b1 = *(const f16x8*)(etb + (size_t)(j0 + js * 16 + lr) * C + 32 + lg * 8);
      #pragma unroll
      for (int is = 0; is < 4; ++is) {
        f32x4 z = {0.f, 0.f, 0.f, 0.f};
        f32x4 S = MFMA16(a[is][0], b0, z);
        S = MFMA16(a[is][1], b1, S);
        #pragma unroll
        for (int r = 0; r < 4; ++r) lacc[is][r] += __expf(S[r] - ms4[is][r]);
      }
    }
  }

  #pragma unroll
  for (int m = 1; m < 16; m <<= 1)
    #pragma unroll
    for (int is = 0; is < 4; ++is)
      #pragma unroll
      for (int r = 0; r < 4; ++r) lacc[is][r] += __shfl_xor(lacc[is][r], m);

  if (lr == 0)
    #pragma unroll
    for (int is = 0; is < 4; ++is)
      #pragma unroll
      for (int r = 0; r < 4; ++r) lpart[wv][is * 16 + lg * 4 + r] = lacc[is][r];
  __syncthreads();

  if (tid < 64)
    lpartial[((size_t)b * HW + i0 + tid) * 4 + jq] =
        lpart[0][tid] + lpart[1][tid] + lpart[2][tid] + lpart[3][tid];
}

// ---------------- Kernel C: partial^T[iq] += P^T . e^T  (out^T = sum_i) -------------
// 512 blocks = (b:4, jb:16 of 256 j, iq:8 of 512 i). 256 thr = 4 waves, 64 j per wave.
#define ETS 72   // etL row stride (f16)
#define ECS 40   // ecL row stride
__global__ __launch_bounds__(256) __attribute__((amdgpu_waves_per_eu(2, 4)))
void k_out(
    const f16* __restrict__ et, const f16* __restrict__ ec,
    const float* __restrict__ mbuf, const float* __restrict__ lpartial,
    f16* __restrict__ partial)
{
  __shared__ __align__(16) f16 etL[2][32][ETS];    // [i][c]
  __shared__ __align__(16) f16 ecL[2][64][ECS];    // [c][i]
  __shared__ __align__(16) f16 maugAll[513][8];    // [m~, dhi, dlo, 0...]; row 512 = zeros
  const int blk = swz_blk512();
  const int b  = blk >> 7;
  const int jb = (blk >> 3) & 15;
  const int iq = blk & 7;
  const int tid = threadIdx.x;
  const int w = tid >> 6;          // 0..3
  const int lane = tid & 63;
  const int l31 = lane & 31;
  const int h = lane >> 5;
  const int jbase = jb * 256 + w * 64;   // wave owns 64 j (2 jt tiles of 32)
  const int ibase = iq * 512;

  const f16* etb = et + (size_t)b * HW * C;
  const f16* ecb = ec + (size_t)b * C * HW;

  // per-i softmax constants for the block's 512 i (2 rows per thread)
  #pragma unroll
  for (int rr = 0; rr < 2; ++rr) {
    int i = tid + rr * 256;
    float m = mbuf[(size_t)b * HW + ibase + i];
    f32x4 lp = *(const f32x4*)&lpartial[((size_t)b * HW + ibase + i) * 4];
    float l = lp[0] + lp[1] + lp[2] + lp[3];
    float d = __logf(l);
    f16 dh = (f16)d;
    f16 dl = (f16)(d - (float)dh);
    f16x8 row = {};
    row[0] = (f16)m; row[1] = dh; row[2] = dl;
    *(f16x8*)&maugAll[i][0] = row;
  }
  if (tid == 0) { f16x8 zz = {}; *(f16x8*)&maugAll[512][0] = zz; }

  // constant aug B-fragment: -1 at k_local 0,1,2 (h=0 lanes), 0 elsewhere
  f16x8 baug = {};
  if (h == 0) { baug[0] = (f16)-1.f; baug[1] = (f16)-1.f; baug[2] = (f16)-1.f; }

  // score B fragments (regs, fixed): 2 jt tiles x 4 K-chunks of 16 c
  f16x8 bj[2][4];
  #pragma unroll
  for (int jt = 0; jt < 2; ++jt)
    #pragma unroll
    for (int kc = 0; kc < 4; ++kc)
      bj[jt][kc] = *(const f16x8*)(etb + (size_t)(jbase + jt * 32 + l31) * C + kc * 16 + h * 8);

  f32x16 acc[2][2] = {};   // [jt][cs] of out^T (m=j, n=c)

  // staging: EVERY thread stages one et vector and one ec vector per chunk
  const int sei = tid >> 3;          // et row 0..31
  const int sec = (tid & 7) * 8;     // et col
  const int scc = tid >> 2;          // ec row (c) 0..63
  const int sci = (tid & 3) * 8;     // ec col (i)

  *(f16x8*)&etL[0][sei][sec] = *(const f16x8*)(etb + (size_t)(ibase + sei) * C + sec);
  *(f16x8*)&ecL[0][scc][sci] = *(const f16x8*)(ecb + (size_t)scc * HW + ibase + sci);
  __syncthreads();

  for (int t = 0; t < 16; ++t) {
    const int cur = t & 1;
    const int i0c = ibase + t * 32;

    f16x8 sve, svc;
    if (t < 15) {
      sve = *(const f16x8*)(etb + (size_t)(i0c + 32 + sei) * C + sec);
      svc = *(const f16x8*)(ecb + (size_t)scc * HW + (i0c + 32) + sci);
    }

    f16x8 bv[2][2];
    #pragma unroll
    for (int cs = 0; cs < 2; ++cs)
      #pragma unroll
      for (int kf = 0; kf < 2; ++kf)
        bv[cs][kf] = *(const f16x8*)&ecL[cur][cs * 32 + l31][kf * 16 + h * 8];

    f16x8 af[4];
    #pragma unroll
    for (int kc = 0; kc < 4; ++kc)
      af[kc] = *(const f16x8*)&etL[cur][l31][kc * 16 + h * 8];
    f16x8 aaug = *(const f16x8*)&maugAll[h ? 512 : (t * 32 + l31)][0];

    #pragma unroll
    for (int jt = 0; jt < 2; ++jt) {
      // S' = e_i . e_j - m~_i - ln(l_i)
      f32x16 z = {};
      f32x16 S = MFMA32(af[0], bj[jt][0], z);
      S = MFMA32(af[1], bj[jt][1], S);
      S = MFMA32(af[2], bj[jt][2], S);
      S = MFMA32(af[3], bj[jt][3], S);
      S = MFMA32(aaug, baug, S);

      // P = exp(S'); repack to PV A-frag (lane=j, k=i) via pkrtz + permlane32_swap
      f16x8 pa[2];
      #pragma unroll
      for (int kf = 0; kf < 2; ++kf) {
        int A0 = __builtin_bit_cast(int, __builtin_amdgcn_cvt_pkrtz(__expf(S[kf * 8 + 0]), __expf(S[kf * 8 + 1])));
        int A1 = __builtin_bit_cast(int, __builtin_amdgcn_cvt_pkrtz(__expf(S[kf * 8 + 2]), __expf(S[kf * 8 + 3])));
        int B0 = __builtin_bit_cast(int, __builtin_amdgcn_cvt_pkrtz(__expf(S[kf * 8 + 4]), __expf(S[kf * 8 + 5])));
        int B1 = __builtin_bit_cast(int, __builtin_amdgcn_cvt_pkrtz(__expf(S[kf * 8 + 6]), __expf(S[kf * 8 + 7])));
        // HW semantic: vdst.hi <-> vsrc.lo. vdst=A (low rows), vsrc=B (high rows).
        asm volatile("v_permlane32_swap_b32 %0, %1" : "+v"(A0), "+v"(B0));
        asm volatile("v_permlane32_swap_b32 %0, %1" : "+v"(A1), "+v"(B1));
        i32x4 fri = {A0, A1, B0, B1};
        pa[kf] = __builtin_bit_cast(f16x8, fri);
      }

      acc[jt][0] = MFMA32(pa[0], bv[0][0], acc[jt][0]);
      acc[jt][1] = MFMA32(pa[0], bv[1][0], acc[jt][1]);
      acc[jt][0] = MFMA32(pa[1], bv[0][1], acc[jt][0]);
      acc[jt][1] = MFMA32(pa[1], bv[1][1], acc[jt][1]);
    }

    if (t < 15) {
      *(f16x8*)&etL[cur ^ 1][sei][sec] = sve;
      *(f16x8*)&ecL[cur ^ 1][scc][sci] = svc;
    }
    __syncthreads();
  }

  // partial[iq][b][j][c] (out^T layout -> coalesced: lanes vary c)
  f16* pb = partial + (size_t)(iq * B + b) * HW * C;
  #pragma unroll
  for (int jt = 0; jt < 2; ++jt)
    #pragma unroll
    for (int cs = 0; cs < 2; ++cs)
      #pragma unroll
      for (int r = 0; r < 16; ++r) {
        int j = jbase + jt * 32 + (r & 3) + 8 * (r >> 2) + 4 * h;
        pb[(size_t)j * C + cs * 32 + l31] = (f16)acc[jt][cs][r];
      }
}

// ---------------- Kernel D: out[c][j] = x + sum_iq partial[iq][j][c] (transpose) ----
// 512 blocks = (b:4, 128 j-tiles of 32) x 512 thr: iq split across two 256-thread
// halves (each sums 4 partials) -> 16 waves/CU, half the dependent-load chain.
__global__ __launch_bounds__(512) void k_reduce(
    const f16* __restrict__ partial, const float* __restrict__ x, float* __restrict__ out)
{
  __shared__ float tile[2][32][65];
  const int blk = swz_blk512();
  const int b = blk >> 7;
  const int j0 = (blk & 127) * 32;
  const int tid = threadIdx.x;
  const int g = tid >> 8;          // iq half: 0 -> iq 0..3, 1 -> iq 4..7
  const int t8 = tid & 255;
  const int jj = t8 >> 3, cq = (t8 & 7) * 8;

  float a0[8] = {};
  #pragma unroll
  for (int k = 0; k < 4; ++k) {
    int iq = g * 4 + k;
    const f16* p = partial + ((size_t)(iq * B + b) * HW + j0 + jj) * C + cq;
    f16x8 v = *(const f16x8*)p;
    #pragma unroll
    for (int e = 0; e < 8; ++e) a0[e] += (float)v[e];
  }
  #pragma unroll
  for (int e = 0; e < 8; ++e) tile[g][jj][cq + e] = a0[e];
  __syncthreads();

  // write: jl = tid&31 (j), cx = tid>>5 (0..15) -> 4 channels each; coalesced in jl
  const int jl = tid & 31, cx = tid >> 5;
  #pragma unroll
  for (int k = 0; k < 4; ++k) {
    int c = cx * 4 + k;
    size_t idx = ((size_t)b * C + c) * HW + j0 + jl;
    out[idx] = tile[0][jl][c] + tile[1][jl][c] + x[idx];
  }
}

extern "C" void kernel_launch(void* const* d_in, const int* in_sizes, int n_in,
                              void* d_out, int out_size, void* d_ws, size_t ws_size,
                              hipStream_t stream) {
  const float* x = (const float*)d_in[0];
  const float* W = (const float*)d_in[1];
  const float* bconv = (const float*)d_in[2];
  float* out = (float*)d_out;

  f16* et16 = (f16*)d_ws;
  f16* ec16 = et16 + (size_t)B * HW * C;
  float* mbuf = (float*)(ec16 + (size_t)B * HW * C);
  float* lpartial = mbuf + (size_t)B * HW;               // [B][HW][4] f32
  f16* partial = (f16*)(lpartial + (size_t)B * HW * 4);  // 16 MB; ws total ~20.4 MB

  k_e<<<dim3(256), dim3(256), 0, stream>>>(x, W, bconv, et16, ec16, mbuf);
  k_stats<<<dim3(1024), dim3(256), 0, stream>>>(et16, mbuf, lpartial);
  k_out<<<dim3(512), dim3(256), 0, stream>>>(et16, ec16, mbuf, lpartial, partial);
  k_reduce<<<dim3(512), dim3(512), 0, stream>>>(partial, x, out);
}

// Round 19
// 59.547 us; speedup vs baseline: 1.5183x; 1.0003x over previous
//
#include <hip/hip_runtime.h>
#include <math.h>

#define B 4
#define C 64
#define HW 4096

typedef _Float16 f16;
typedef f16 f16x8 __attribute__((ext_vector_type(8)));
typedef f16 f16x4 __attribute__((ext_vector_type(4)));
typedef float f32x4 __attribute__((ext_vector_type(4)));
typedef float f32x16 __attribute__((ext_vector_type(16)));
typedef int i32x4 __attribute__((ext_vector_type(4)));

#define MFMA16(a,b,c) __builtin_amdgcn_mfma_f32_16x16x32_f16(a,b,c,0,0,0)
#define MFMA32(a,b,c) __builtin_amdgcn_mfma_f32_32x32x16_f16(a,b,c,0,0,0)

// ws layout (~20.4 MB):
//   et16    : [B][HW][C] f16           2 MB
//   ec16    : [B][C][HW] f16           2 MB
//   mbuf    : [B][HW] f32              64 KB
//   lpartial: [B][HW][4] f32           256 KB
//   partial : [8][B][HW][C] f16        16 MB
//
// STRUCTURAL LESSONS (final):
//  - R15: hand-rolled threadfence/atomic cross-block reduction -> stale data. DEAD.
//  - R17: >64 KB static LDS per workgroup silently fails to launch (160 KB is per-CU).
//  - R18: hipLaunchCooperativeKernel is numerically fine live but NOT graph-capturable;
//    harness replays an invalidated graph -> poisoned output. DEAD on this harness.
//  => 4 separate dispatches is the irreducible structure; dispatch boundaries are the
//     only trusted inter-phase sync.
//  - Allocator: __launch_bounds__(N, min_waves) second-arg form is the only knob that
//    raises the 64-VGPR default cap (R13 A/B). amdgpu_waves_per_eu attr does nothing.
//  - LDS row strides must be 16B multiples or f16x8 access splits into 2x ds_read_b64.

// XCD-affine swizzles (8 XCDs x k contiguous logical blocks).
__device__ __forceinline__ int swz_blk()     { int r = blockIdx.x; return (r & 7) * 32  + (r >> 3); }
__device__ __forceinline__ int swz_blk512()  { int r = blockIdx.x; return (r & 7) * 64  + (r >> 3); }
__device__ __forceinline__ int swz_blk1024() { int r = blockIdx.x; return (r & 7) * 128 + (r >> 3); }

// ---------------- Kernel A: e = W @ x + bconv -> et16, ec16, mbuf -------------------
__global__ __launch_bounds__(256) void k_e(
    const float* __restrict__ x, const float* __restrict__ W,
    const float* __restrict__ bconv, f16* __restrict__ et, f16* __restrict__ ec,
    float* __restrict__ mbuf)
{
  __shared__ float Ws[64][65];
  __shared__ __align__(16) float xs[64][64];
  __shared__ __align__(16) f16 es[64][72];
  __shared__ float msp[4][64];
  const int blk = swz_blk();
  const int b = blk >> 6;
  const int i0 = (blk & 63) * 64;
  const int tid = threadIdx.x;

  for (int k = tid; k < 64 * 64; k += 256) Ws[k >> 6][k & 63] = W[k];
  {
    const float* xb = x + (size_t)b * C * HW + i0;
    #pragma unroll
    for (int it = 0; it < 4; ++it) {
      int idx = tid + it * 256;
      int r = idx >> 4, c4 = (idx & 15) * 4;
      f32x4 v = *(const f32x4*)(xb + (size_t)r * HW + c4);
      *(f32x4*)&xs[r][c4] = v;
    }
  }
  __syncthreads();

  const int o = tid & 63;
  const int ig = tid >> 6;
  float acc[16];
  float bv = bconv[o];
  #pragma unroll
  for (int k = 0; k < 16; ++k) acc[k] = bv;
  for (int c = 0; c < C; ++c) {
    float wv = Ws[o][c];
    #pragma unroll
    for (int k = 0; k < 16; ++k) acc[k] = fmaf(wv, xs[c][ig * 16 + k], acc[k]);
  }
  #pragma unroll
  for (int k = 0; k < 16; ++k) {
    int ii = ig * 16 + k;
    f16 v = (f16)acc[k];
    et[((size_t)b * HW + i0 + ii) * C + o] = v;
    es[o][ii] = v;
  }
  __syncthreads();

  // ec transpose (f16x4 vectorized stores)
  {
    const int ii4 = (tid & 15) * 4;
    const int ob = tid >> 4;
    #pragma unroll
    for (int k = 0; k < 4; ++k) {
      int oo = ob + 16 * k;
      f16x4 v = *(const f16x4*)&es[oo][ii4];
      *(f16x4*)&ec[((size_t)b * C + oo) * HW + i0 + ii4] = v;
    }
  }

  // m_i = |e_i|^2 (sum over channels, fp32 accum)
  const int ii = tid & 63, og = tid >> 6;
  {
    float s = 0.f;
    #pragma unroll
    for (int k = 0; k < 16; ++k) {
      float v = (float)es[og * 16 + k][ii];
      s = fmaf(v, v, s);
    }
    msp[og][ii] = s;
  }
  __syncthreads();
  if (tid < 64) {
    float mm = msp[0][tid] + msp[1][tid] + msp[2][tid] + msp[3][tid];
    mbuf[(size_t)b * HW + i0 + tid] = (float)(f16)mm;   // f16-canonical shift
  }
}

// ---------------- Kernel B: split-j softmax partials -------------------------------
// 1024 blocks = (b:4, ib:64 of 64 i-rows, jq:4 of 1024 j) x 256 thr (4 waves).
__global__ __launch_bounds__(256, 2)
void k_stats(const f16* __restrict__ et, const float* __restrict__ mbuf,
             float* __restrict__ lpartial)
{
  __shared__ float lpart[4][68];
  const int blk = swz_blk1024();
  const int b  = blk >> 8;
  const int ib = (blk >> 2) & 63;
  const int jq = blk & 3;
  const int i0 = ib * 64;
  const int tid = threadIdx.x;
  const int wv = tid >> 6;
  const int lane = tid & 63;
  const int lr = lane & 15, lg = lane >> 4;
  const f16* etb = et + (size_t)b * HW * C;

  f16x8 a[4][2];
  #pragma unroll
  for (int is = 0; is < 4; ++is)
    #pragma unroll
    for (int kc = 0; kc < 2; ++kc)
      a[is][kc] = *(const f16x8*)(etb + (size_t)(i0 + is * 16 + lr) * C + kc * 32 + lg * 8);

  f32x4 ms4[4];
  #pragma unroll
  for (int is = 0; is < 4; ++is)
    ms4[is] = *(const f32x4*)(mbuf + (size_t)b * HW + i0 + is * 16 + lg * 4);

  float lacc[4][4] = {};
  for (int t = 0; t < 8; ++t) {
    const int j0 = jq * 1024 + (wv + 4 * t) * 32;
    #pragma unroll
    for (int js = 0; js < 2; ++js) {
      f16x8 b0 = *(const f16x8*)(etb + (size_t)(j0 + js * 16 + lr) * C + lg * 8);
      f16x8 b1 = *(const f16x8*)(etb + (size_t)(j0 + js * 16 + lr) * C + 32 + lg * 8);
      #pragma unroll
      for (int is = 0; is < 4; ++is) {
        f32x4 z = {0.f, 0.f, 0.f, 0.f};
        f32x4 S = MFMA16(a[is][0], b0, z);
        S = MFMA16(a[is][1], b1, S);
        #pragma unroll
        for (int r = 0; r < 4; ++r) lacc[is][r] += __expf(S[r] - ms4[is][r]);
      }
    }
  }

  #pragma unroll
  for (int m = 1; m < 16; m <<= 1)
    #pragma unroll
    for (int is = 0; is < 4; ++is)
      #pragma unroll
      for (int r = 0; r < 4; ++r) lacc[is][r] += __shfl_xor(lacc[is][r], m);

  if (lr == 0)
    #pragma unroll
    for (int is = 0; is < 4; ++is)
      #pragma unroll
      for (int r = 0; r < 4; ++r) lpart[wv][is * 16 + lg * 4 + r] = lacc[is][r];
  __syncthreads();

  if (tid < 64)
    lpartial[((size_t)b * HW + i0 + tid) * 4 + jq] =
        lpart[0][tid] + lpart[1][tid] + lpart[2][tid] + lpart[3][tid];
}

// ---------------- Kernel C: partial^T[iq] += P^T . e^T  (out^T = sum_i) -------------
// 512 blocks = (b:4, jb:16 of 256 j, iq:8 of 512 i). 256 thr = 4 waves, 64 j per wave.
#define ETS 72   // etL row stride (f16)
#define ECS 40   // ecL row stride
__global__ __launch_bounds__(256) __attribute__((amdgpu_waves_per_eu(2, 4)))
void k_out(
    const f16* __restrict__ et, const f16* __restrict__ ec,
    const float* __restrict__ mbuf, const float* __restrict__ lpartial,
    f16* __restrict__ partial)
{
  __shared__ __align__(16) f16 etL[2][32][ETS];    // [i][c]
  __shared__ __align__(16) f16 ecL[2][64][ECS];    // [c][i]
  __shared__ __align__(16) f16 maugAll[513][8];    // [m~, dhi, dlo, 0...]; row 512 = zeros
  const int blk = swz_blk512();
  const int b  = blk >> 7;
  const int jb = (blk >> 3) & 15;
  const int iq = blk & 7;
  const int tid = threadIdx.x;
  const int w = tid >> 6;          // 0..3
  const int lane = tid & 63;
  const int l31 = lane & 31;
  const int h = lane >> 5;
  const int jbase = jb * 256 + w * 64;   // wave owns 64 j (2 jt tiles of 32)
  const int ibase = iq * 512;

  const f16* etb = et + (size_t)b * HW * C;
  const f16* ecb = ec + (size_t)b * C * HW;

  // per-i softmax constants for the block's 512 i (2 rows per thread)
  #pragma unroll
  for (int rr = 0; rr < 2; ++rr) {
    int i = tid + rr * 256;
    float m = mbuf[(size_t)b * HW + ibase + i];
    f32x4 lp = *(const f32x4*)&lpartial[((size_t)b * HW + ibase + i) * 4];
    float l = lp[0] + lp[1] + lp[2] + lp[3];
    float d = __logf(l);
    f16 dh = (f16)d;
    f16 dl = (f16)(d - (float)dh);
    f16x8 row = {};
    row[0] = (f16)m; row[1] = dh; row[2] = dl;
    *(f16x8*)&maugAll[i][0] = row;
  }
  if (tid == 0) { f16x8 zz = {}; *(f16x8*)&maugAll[512][0] = zz; }

  // constant aug B-fragment: -1 at k_local 0,1,2 (h=0 lanes), 0 elsewhere
  f16x8 baug = {};
  if (h == 0) { baug[0] = (f16)-1.f; baug[1] = (f16)-1.f; baug[2] = (f16)-1.f; }

  // score B fragments (regs, fixed): 2 jt tiles x 4 K-chunks of 16 c
  f16x8 bj[2][4];
  #pragma unroll
  for (int jt = 0; jt < 2; ++jt)
    #pragma unroll
    for (int kc = 0; kc < 4; ++kc)
      bj[jt][kc] = *(const f16x8*)(etb + (size_t)(jbase + jt * 32 + l31) * C + kc * 16 + h * 8);

  f32x16 acc[2][2] = {};   // [jt][cs] of out^T (m=j, n=c)

  // staging: EVERY thread stages one et vector and one ec vector per chunk
  const int sei = tid >> 3;          // et row 0..31
  const int sec = (tid & 7) * 8;     // et col
  const int scc = tid >> 2;          // ec row (c) 0..63
  const int sci = (tid & 3) * 8;     // ec col (i)

  *(f16x8*)&etL[0][sei][sec] = *(const f16x8*)(etb + (size_t)(ibase + sei) * C + sec);
  *(f16x8*)&ecL[0][scc][sci] = *(const f16x8*)(ecb + (size_t)scc * HW + ibase + sci);
  __syncthreads();

  for (int t = 0; t < 16; ++t) {
    const int cur = t & 1;
    const int i0c = ibase + t * 32;

    f16x8 sve, svc;
    if (t < 15) {
      sve = *(const f16x8*)(etb + (size_t)(i0c + 32 + sei) * C + sec);
      svc = *(const f16x8*)(ecb + (size_t)scc * HW + (i0c + 32) + sci);
    }

    f16x8 bv[2][2];
    #pragma unroll
    for (int cs = 0; cs < 2; ++cs)
      #pragma unroll
      for (int kf = 0; kf < 2; ++kf)
        bv[cs][kf] = *(const f16x8*)&ecL[cur][cs * 32 + l31][kf * 16 + h * 8];

    f16x8 af[4];
    #pragma unroll
    for (int kc = 0; kc < 4; ++kc)
      af[kc] = *(const f16x8*)&etL[cur][l31][kc * 16 + h * 8];
    f16x8 aaug = *(const f16x8*)&maugAll[h ? 512 : (t * 32 + l31)][0];

    #pragma unroll
    for (int jt = 0; jt < 2; ++jt) {
      // S' = e_i . e_j - m~_i - ln(l_i)
      f32x16 z = {};
      f32x16 S = MFMA32(af[0], bj[jt][0], z);
      S = MFMA32(af[1], bj[jt][1], S);
      S = MFMA32(af[2], bj[jt][2], S);
      S = MFMA32(af[3], bj[jt][3], S);
      S = MFMA32(aaug, baug, S);

      // P = exp(S'); repack to PV A-frag (lane=j, k=i) via pkrtz + permlane32_swap
      f16x8 pa[2];
      #pragma unroll
      for (int kf = 0; kf < 2; ++kf) {
        int A0 = __builtin_bit_cast(int, __builtin_amdgcn_cvt_pkrtz(__expf(S[kf * 8 + 0]), __expf(S[kf * 8 + 1])));
        int A1 = __builtin_bit_cast(int, __builtin_amdgcn_cvt_pkrtz(__expf(S[kf * 8 + 2]), __expf(S[kf * 8 + 3])));
        int B0 = __builtin_bit_cast(int, __builtin_amdgcn_cvt_pkrtz(__expf(S[kf * 8 + 4]), __expf(S[kf * 8 + 5])));
        int B1 = __builtin_bit_cast(int, __builtin_amdgcn_cvt_pkrtz(__expf(S[kf * 8 + 6]), __expf(S[kf * 8 + 7])));
        // HW semantic: vdst.hi <-> vsrc.lo. vdst=A (low rows), vsrc=B (high rows).
        asm volatile("v_permlane32_swap_b32 %0, %1" : "+v"(A0), "+v"(B0));
        asm volatile("v_permlane32_swap_b32 %0, %1" : "+v"(A1), "+v"(B1));
        i32x4 fri = {A0, A1, B0, B1};
        pa[kf] = __builtin_bit_cast(f16x8, fri);
      }

      acc[jt][0] = MFMA32(pa[0], bv[0][0], acc[jt][0]);
      acc[jt][1] = MFMA32(pa[0], bv[1][0], acc[jt][1]);
      acc[jt][0] = MFMA32(pa[1], bv[0][1], acc[jt][0]);
      acc[jt][1] = MFMA32(pa[1], bv[1][1], acc[jt][1]);
    }

    if (t < 15) {
      *(f16x8*)&etL[cur ^ 1][sei][sec] = sve;
      *(f16x8*)&ecL[cur ^ 1][scc][sci] = svc;
    }
    __syncthreads();
  }

  // partial[iq][b][j][c] (out^T layout -> coalesced: lanes vary c)
  f16* pb = partial + (size_t)(iq * B + b) * HW * C;
  #pragma unroll
  for (int jt = 0; jt < 2; ++jt)
    #pragma unroll
    for (int cs = 0; cs < 2; ++cs)
      #pragma unroll
      for (int r = 0; r < 16; ++r) {
        int j = jbase + jt * 32 + (r & 3) + 8 * (r >> 2) + 4 * h;
        pb[(size_t)j * C + cs * 32 + l31] = (f16)acc[jt][cs][r];
      }
}

// ---------------- Kernel D: out[c][j] = x + sum_iq partial[iq][j][c] (transpose) ----
// 512 blocks = (b:4, 128 j-tiles of 32) x 512 thr: iq split across two halves.
__global__ __launch_bounds__(512) void k_reduce(
    const f16* __restrict__ partial, const float* __restrict__ x, float* __restrict__ out)
{
  __shared__ float tile[2][32][65];
  const int blk = swz_blk512();
  const int b = blk >> 7;
  const int j0 = (blk & 127) * 32;
  const int tid = threadIdx.x;
  const int g = tid >> 8;          // iq half: 0 -> iq 0..3, 1 -> iq 4..7
  const int t8 = tid & 255;
  const int jj = t8 >> 3, cq = (t8 & 7) * 8;

  float a0[8] = {};
  #pragma unroll
  for (int k = 0; k < 4; ++k) {
    int iq = g * 4 + k;
    const f16* p = partial + ((size_t)(iq * B + b) * HW + j0 + jj) * C + cq;
    f16x8 v = *(const f16x8*)p;
    #pragma unroll
    for (int e = 0; e < 8; ++e) a0[e] += (float)v[e];
  }
  #pragma unroll
  for (int e = 0; e < 8; ++e) tile[g][jj][cq + e] = a0[e];
  __syncthreads();

  const int jl = tid & 31, cx = tid >> 5;
  #pragma unroll
  for (int k = 0; k < 4; ++k) {
    int c = cx * 4 + k;
    size_t idx = ((size_t)b * C + c) * HW + j0 + jl;
    out[idx] = tile[0][jl][c] + tile[1][jl][c] + x[idx];
  }
}

extern "C" void kernel_launch(void* const* d_in, const int* in_sizes, int n_in,
                              void* d_out, int out_size, void* d_ws, size_t ws_size,
                              hipStream_t stream) {
  const float* x = (const float*)d_in[0];
  const float* W = (const float*)d_in[1];
  const float* bconv = (const float*)d_in[2];
  float* out = (float*)d_out;

  f16* et16 = (f16*)d_ws;
  f16* ec16 = et16 + (size_t)B * HW * C;
  float* mbuf = (float*)(ec16 + (size_t)B * HW * C);
  float* lpartial = mbuf + (size_t)B * HW;               // [B][HW][4] f32
  f16* partial = (f16*)(lpartial + (size_t)B * HW * 4);  // 16 MB; ws total ~20.4 MB

  k_e<<<dim3(256), dim3(256), 0, stream>>>(x, W, bconv, et16, ec16, mbuf);
  k_stats<<<dim3(1024), dim3(256), 0, stream>>>(et16, mbuf, lpartial);
  k_out<<<dim3(512), dim3(256), 0, stream>>>(et16, ec16, mbuf, lpartial, partial);
  k_reduce<<<dim3(512), dim3(512), 0, stream>>>(partial, x, out);
}